// Round 1
// baseline (9359.185 us; speedup 1.0000x reference)
//
#include <hip/hip_runtime.h>
#include <hip/hip_bf16.h>
#include <math.h>

#define N_TOK 8192
#define DMODEL 512
#define NHEAD 8
#define HDIM 64
#define SEQ 512
#define BATCH 16
#define FFDIM 2048
#define NLAYER 6
#define NCLS 10000

// ---------------- positional table (fp64 to match np.float64 reference) ------
__global__ __launch_bounds__(256) void pos_kernel(float* __restrict__ pos) {
    const int idx = blockIdx.x * 256 + threadIdx.x;   // 512*512 = 262144
    const int s = idx >> 9, i = idx & 511;
    const double expo = (double)(i & ~1) / 512.0;
    const double ang = (double)s / pow(10000.0, expo);
    pos[idx] = (float)((i & 1) ? cos(ang) : sin(ang));
}

// ---------------- embedding: C = 2*emb[x] + pos ------------------------------
__global__ __launch_bounds__(256) void embed_kernel(const int* __restrict__ xi,
        const float* __restrict__ emb, const float* __restrict__ pos,
        float* __restrict__ C) {
    const int idx = blockIdx.x * 256 + threadIdx.x;   // over N_TOK*128 float4s
    const int n = idx >> 7, d4 = (idx & 127) << 2;
    const int row = xi[n];
    const int s = n & 511;
    const float4 e = *(const float4*)&emb[(size_t)row * 512 + d4];
    const float4 p = *(const float4*)&pos[(size_t)s * 512 + d4];
    float4 o;
    o.x = 2.f * e.x + p.x; o.y = 2.f * e.y + p.y;
    o.z = 2.f * e.z + p.z; o.w = 2.f * e.w + p.w;
    *(float4*)&C[(size_t)n * 512 + d4] = o;
}

// ---------------- f32 tiled GEMM ---------------------------------------------
// C[M,N] = A[M,K] * (BT ? B[N,K]^T : B[K,N]).  128x128 tile, BK=16, 8x8/thread.
enum { EPI_PLAIN = 0, EPI_BIAS_RELU = 1, EPI_BIAS = 2, EPI_QKV = 3 };

template<bool BT, int EPI>
__global__ __launch_bounds__(256)
void gemm_f32(const float* __restrict__ A, const float* __restrict__ B,
              const float* __restrict__ bias, float* __restrict__ C,
              int M, int N, int K) {
    __shared__ float As[16][132];
    __shared__ float Bs[16][132];
    const int tid = threadIdx.x;
    const int tx = tid & 15, ty = tid >> 4;
    const int bm = blockIdx.x * 128, bn = blockIdx.y * 128;
    const int ar = tid >> 1, ak = (tid & 1) << 3;
    float acc[8][8] = {};
    for (int k0 = 0; k0 < K; k0 += 16) {
        {   // A tile, transposed into LDS: As[k][m]
            const float4 v0 = *(const float4*)&A[(size_t)(bm + ar) * K + k0 + ak];
            const float4 v1 = *(const float4*)&A[(size_t)(bm + ar) * K + k0 + ak + 4];
            As[ak+0][ar] = v0.x; As[ak+1][ar] = v0.y; As[ak+2][ar] = v0.z; As[ak+3][ar] = v0.w;
            As[ak+4][ar] = v1.x; As[ak+5][ar] = v1.y; As[ak+6][ar] = v1.z; As[ak+7][ar] = v1.w;
        }
        if (BT) {   // B is [N][K] row-major
            const float4 v0 = *(const float4*)&B[(size_t)(bn + ar) * K + k0 + ak];
            const float4 v1 = *(const float4*)&B[(size_t)(bn + ar) * K + k0 + ak + 4];
            Bs[ak+0][ar] = v0.x; Bs[ak+1][ar] = v0.y; Bs[ak+2][ar] = v0.z; Bs[ak+3][ar] = v0.w;
            Bs[ak+4][ar] = v1.x; Bs[ak+5][ar] = v1.y; Bs[ak+6][ar] = v1.z; Bs[ak+7][ar] = v1.w;
        } else {    // B is [K][N] row-major
            const int bk = ty, bnn = tx << 3;
            const float4 v0 = *(const float4*)&B[(size_t)(k0 + bk) * N + bn + bnn];
            const float4 v1 = *(const float4*)&B[(size_t)(k0 + bk) * N + bn + bnn + 4];
            *(float4*)&Bs[bk][bnn]     = v0;
            *(float4*)&Bs[bk][bnn + 4] = v1;
        }
        __syncthreads();
        #pragma unroll
        for (int kk = 0; kk < 16; ++kk) {
            float a[8], b[8];
            *(float4*)&a[0] = *(const float4*)&As[kk][ty << 3];
            *(float4*)&a[4] = *(const float4*)&As[kk][(ty << 3) + 4];
            *(float4*)&b[0] = *(const float4*)&Bs[kk][tx << 3];
            *(float4*)&b[4] = *(const float4*)&Bs[kk][(tx << 3) + 4];
            #pragma unroll
            for (int i = 0; i < 8; ++i)
                #pragma unroll
                for (int j = 0; j < 8; ++j)
                    acc[i][j] = fmaf(a[i], b[j], acc[i][j]);
        }
        __syncthreads();
    }
    if (EPI == EPI_QKV) {
        // head-deinterleave: col n -> head n%8, dim n/8 ; out layout [H][N_TOK][64]
        #pragma unroll
        for (int i = 0; i < 8; ++i) {
            const int m = bm + (ty << 3) + i;
            #pragma unroll
            for (int j = 0; j < 8; ++j) {
                const int n = bn + (tx << 3) + j;
                C[((size_t)(n & 7) * N_TOK + m) * 64 + (n >> 3)] = acc[i][j];
            }
        }
    } else {
        #pragma unroll
        for (int i = 0; i < 8; ++i) {
            const int m = bm + (ty << 3) + i;
            const int n0 = bn + (tx << 3);
            float vv[8];
            #pragma unroll
            for (int j = 0; j < 8; ++j) {
                float v = acc[i][j];
                if (EPI == EPI_BIAS_RELU) { v += bias[n0 + j]; v = fmaxf(v, 0.f); }
                if (EPI == EPI_BIAS)      { v += bias[n0 + j]; }
                vv[j] = v;
            }
            *(float4*)&C[(size_t)m * N + n0]     = *(float4*)&vv[0];
            *(float4*)&C[(size_t)m * N + n0 + 4] = *(float4*)&vv[4];
        }
    }
}

// ---------------- fused attention (scores + norm(t) + softmax + PV) ----------
// grid: 512 blocks = (h, b, s-quarter). 256 thr = 4 waves; wave w owns row s0+w.
__global__ __launch_bounds__(256)
void attn_kernel(const float* __restrict__ Q, const float* __restrict__ K,
                 const float* __restrict__ V, const float* __restrict__ ga,
                 const float* __restrict__ ba, float* __restrict__ A, float scale) {
    __shared__ float Kt[64][129];   // [kk][t-chunk(128)+pad] : conflict-free both sides
    __shared__ float q_s[4][64];
    __shared__ float al[4][512];
    const int bid = blockIdx.x;
    const int h = bid & 7, b = (bid >> 3) & 15, qr = bid >> 7;
    const int tid = threadIdx.x, w = tid >> 6, l = tid & 63;
    const float gah = ga[h], bah = ba[h];
    const size_t base = ((size_t)h * N_TOK + (size_t)b * SEQ) * 64;
    const float* Qg = Q + base;
    const float* Kg = K + base;
    const float* Vg = V + base;

    for (int pass = 0; pass < 32; ++pass) {
        const int s0 = qr * 128 + pass * 4;
        __syncthreads();
        q_s[w][l] = Qg[(size_t)(s0 + w) * 64 + l];
        float sc[8];   // score for t = idx*64 + l
        #pragma unroll
        for (int ch = 0; ch < 4; ++ch) {
            __syncthreads();
            #pragma unroll 8
            for (int i = 0; i < 32; ++i) {   // stage K chunk transposed
                const int t = i * 4 + w;
                Kt[l][t] = Kg[(size_t)(ch * 128 + t) * 64 + l];
            }
            __syncthreads();
            float a0 = 0.f, a1 = 0.f;
            #pragma unroll 16
            for (int kk = 0; kk < 64; ++kk) {
                const float qv = q_s[w][kk];
                a0 = fmaf(qv, Kt[kk][l], a0);
                a1 = fmaf(qv, Kt[kk][64 + l], a1);
            }
            sc[ch * 2 + 0] = a0;
            sc[ch * 2 + 1] = a1;
        }
        // scale, then mean/var (ddof=1) over the 512 scores of this row
        float sum = 0.f, sq = 0.f;
        #pragma unroll
        for (int r = 0; r < 8; ++r) {
            sc[r] *= scale;
            sum += sc[r];
            sq = fmaf(sc[r], sc[r], sq);
        }
        #pragma unroll
        for (int o = 1; o < 64; o <<= 1) {
            sum += __shfl_xor(sum, o);
            sq  += __shfl_xor(sq, o);
        }
        const float mu   = sum * (1.f / 512.f);
        const float var  = (sq - 512.f * mu * mu) * (1.f / 511.f);
        const float rstd = rsqrtf(var + 1e-8f);
        float mx = -1e30f;
        #pragma unroll
        for (int r = 0; r < 8; ++r) {
            sc[r] = fmaf((sc[r] - mu) * rstd, gah, bah);
            mx = fmaxf(mx, sc[r]);
        }
        #pragma unroll
        for (int o = 1; o < 64; o <<= 1) mx = fmaxf(mx, __shfl_xor(mx, o));
        float es = 0.f;
        #pragma unroll
        for (int r = 0; r < 8; ++r) { sc[r] = expf(sc[r] - mx); es += sc[r]; }
        #pragma unroll
        for (int o = 1; o < 64; o <<= 1) es += __shfl_xor(es, o);
        const float inv = 1.f / es;
        #pragma unroll
        for (int r = 0; r < 8; ++r) al[w][r * 64 + l] = sc[r] * inv;
        __syncthreads();
        // PV: thread (w=row, l=dd)
        float acc = 0.f;
        #pragma unroll 8
        for (int t = 0; t < 512; ++t)
            acc = fmaf(al[w][t], Vg[(size_t)t * 64 + l], acc);
        // concat layout: A[n][h*64 + dd]
        A[((size_t)(b * SEQ + s0 + w)) * 512 + h * 64 + l] = acc;
    }
}

// ---------------- LayerNorm(X + R) with scalar gamma/beta; optional C += y ----
__global__ __launch_bounds__(256)
void ln_res_kernel(const float* __restrict__ X, const float* __restrict__ R,
                   const float* __restrict__ gp, const float* __restrict__ bp,
                   int lidx, float* __restrict__ Y, float* __restrict__ Cacc) {
    const int tid = threadIdx.x, w = tid >> 6, l = tid & 63;
    const size_t row = (size_t)blockIdx.x * 4 + w;
    const float g = gp[lidx], bb = bp[lidx];
    const float* x = X + row * 512;
    const float* r = R + row * 512;
    float v[8];
    const float4 a0 = *(const float4*)&x[l * 8], a1 = *(const float4*)&x[l * 8 + 4];
    const float4 r0 = *(const float4*)&r[l * 8], r1 = *(const float4*)&r[l * 8 + 4];
    v[0] = a0.x + r0.x; v[1] = a0.y + r0.y; v[2] = a0.z + r0.z; v[3] = a0.w + r0.w;
    v[4] = a1.x + r1.x; v[5] = a1.y + r1.y; v[6] = a1.z + r1.z; v[7] = a1.w + r1.w;
    float s = 0.f, sq = 0.f;
    #pragma unroll
    for (int i = 0; i < 8; ++i) { s += v[i]; sq = fmaf(v[i], v[i], sq); }
    #pragma unroll
    for (int o = 1; o < 64; o <<= 1) { s += __shfl_xor(s, o); sq += __shfl_xor(sq, o); }
    const float mu   = s * (1.f / 512.f);
    const float var  = (sq - 512.f * mu * mu) * (1.f / 511.f);
    const float rstd = rsqrtf(var + 1e-8f);
    float y[8];
    #pragma unroll
    for (int i = 0; i < 8; ++i) y[i] = fmaf((v[i] - mu) * rstd, g, bb);
    *(float4*)&Y[row * 512 + l * 8]     = *(float4*)&y[0];
    *(float4*)&Y[row * 512 + l * 8 + 4] = *(float4*)&y[4];
    if (Cacc) {
        float4 c0 = *(float4*)&Cacc[row * 512 + l * 8];
        float4 c1 = *(float4*)&Cacc[row * 512 + l * 8 + 4];
        c0.x += y[0]; c0.y += y[1]; c0.z += y[2]; c0.w += y[3];
        c1.x += y[4]; c1.y += y[5]; c1.z += y[6]; c1.w += y[7];
        *(float4*)&Cacc[row * 512 + l * 8]     = c0;
        *(float4*)&Cacc[row * 512 + l * 8 + 4] = c1;
    }
}

// ---------------- final head: x9 = X8 @ V_e ----------------------------------
__global__ __launch_bounds__(256)
void fin_ve_kernel(const float* __restrict__ X8, const float* __restrict__ Ve,
                   float* __restrict__ x9) {
    const int tid = threadIdx.x, w = tid >> 6, l = tid & 63;
    const size_t row = (size_t)blockIdx.x * 4 + w;
    const float* x = X8 + row * 512;
    float s = 0.f;
    #pragma unroll
    for (int i = 0; i < 8; ++i) s = fmaf(x[l * 8 + i], Ve[l * 8 + i], s);
    #pragma unroll
    for (int o = 1; o < 64; o <<= 1) s += __shfl_xor(s, o);
    if (l == 0) x9[row] = s;
}

// ---------------- z[b,c] = sum_s x9[b,s] * Vd[s,c] ---------------------------
__global__ __launch_bounds__(256)
void fin_vd_kernel(const float* __restrict__ x9, const float* __restrict__ Vd,
                   float* __restrict__ z) {
    __shared__ float red[4][16][65];
    const int tid = threadIdx.x, l = tid & 63, sch = tid >> 6;
    const int c = blockIdx.x * 64 + l;
    float acc[16];
    #pragma unroll
    for (int b = 0; b < 16; ++b) acc[b] = 0.f;
    if (c < NCLS) {
        for (int s = sch * 128; s < sch * 128 + 128; ++s) {
            const float vd = Vd[(size_t)s * NCLS + c];
            #pragma unroll
            for (int b = 0; b < 16; ++b) acc[b] = fmaf(x9[b * 512 + s], vd, acc[b]);
        }
    }
    #pragma unroll
    for (int b = 0; b < 16; ++b) red[sch][b][l] = acc[b];
    __syncthreads();
    if (sch == 0 && c < NCLS) {
        #pragma unroll
        for (int b = 0; b < 16; ++b)
            z[(size_t)b * NCLS + c] = red[0][b][l] + red[1][b][l] + red[2][b][l] + red[3][b][l];
    }
}

// ---------------- final norm (ddof=1 over 10000) + softmax -------------------
__global__ __launch_bounds__(256)
void fin_sm_kernel(const float* __restrict__ z, const float* __restrict__ gp,
                   const float* __restrict__ bp, float* __restrict__ out) {
    __shared__ float zs[NCLS];
    __shared__ float red[4];
    __shared__ float red2[4];
    const int b = blockIdx.x, tid = threadIdx.x, w = tid >> 6, l = tid & 63;
    float s = 0.f, sq = 0.f;
    for (int i = tid; i < NCLS; i += 256) {
        const float v = z[(size_t)b * NCLS + i];
        zs[i] = v; s += v; sq = fmaf(v, v, sq);
    }
    #pragma unroll
    for (int o = 1; o < 64; o <<= 1) { s += __shfl_xor(s, o); sq += __shfl_xor(sq, o); }
    if (l == 0) { red[w] = s; red2[w] = sq; }
    __syncthreads();
    s  = red[0] + red[1] + red[2] + red[3];
    sq = red2[0] + red2[1] + red2[2] + red2[3];
    const float mu   = s / 10000.f;
    const float var  = (sq - 10000.f * mu * mu) / 9999.f;
    const float rstd = rsqrtf(var + 1e-8f);
    const float g = gp[0], be = bp[0];
    __syncthreads();   // reads of red/red2 done before they are rewritten below
    float mx = -1e30f;
    for (int i = tid; i < NCLS; i += 256) {
        const float e = fmaf((zs[i] - mu) * rstd, g, be);
        zs[i] = e; mx = fmaxf(mx, e);
    }
    #pragma unroll
    for (int o = 1; o < 64; o <<= 1) mx = fmaxf(mx, __shfl_xor(mx, o));
    if (l == 0) red[w] = mx;
    __syncthreads();
    mx = fmaxf(fmaxf(red[0], red[1]), fmaxf(red[2], red[3]));
    float es = 0.f;
    for (int i = tid; i < NCLS; i += 256) {
        const float p = expf(zs[i] - mx);
        zs[i] = p; es += p;
    }
    #pragma unroll
    for (int o = 1; o < 64; o <<= 1) es += __shfl_xor(es, o);
    if (l == 0) red2[w] = es;
    __syncthreads();
    es = red2[0] + red2[1] + red2[2] + red2[3];
    const float inv = 1.f / es;
    for (int i = tid; i < NCLS; i += 256) out[(size_t)b * NCLS + i] = zs[i] * inv;
}

// =============================================================================
extern "C" void kernel_launch(void* const* d_in, const int* in_sizes, int n_in,
                              void* d_out, int out_size, void* d_ws, size_t ws_size,
                              hipStream_t stream) {
    (void)in_sizes; (void)n_in; (void)out_size; (void)ws_size;
    const int*   xi  = (const int*)d_in[0];
    const float* emb = (const float*)d_in[1];
    const float* WQ  = (const float*)d_in[2];
    const float* WK  = (const float*)d_in[3];
    const float* WV  = (const float*)d_in[4];
    const float* WO  = (const float*)d_in[5];
    const float* W1  = (const float*)d_in[6];
    const float* b1  = (const float*)d_in[7];
    const float* W2  = (const float*)d_in[8];
    const float* b2  = (const float*)d_in[9];
    const float* ga  = (const float*)d_in[10];
    const float* ba  = (const float*)d_in[11];
    const float* g1  = (const float*)d_in[12];
    const float* be1 = (const float*)d_in[13];
    const float* g2  = (const float*)d_in[14];
    const float* be2 = (const float*)d_in[15];
    const float* Ve  = (const float*)d_in[16];
    const float* Vd  = (const float*)d_in[17];
    const float* gf  = (const float*)d_in[18];
    const float* bf  = (const float*)d_in[19];
    float* out = (float*)d_out;

    // workspace layout (floats); BIG is reused: Q|K|V|A during attn, H during FF
    float* ws  = (float*)d_ws;
    float* pos = ws;                        // 262144
    float* C   = pos + 262144;              // 4M floats each below
    float* X2  = C   + 4194304;
    float* OUT = X2  + 4194304;
    float* PF  = OUT + 4194304;             // WO-out / W2-out
    float* BIG = PF  + 4194304;             // 16777216 floats
    float* Qb = BIG;
    float* Kb = BIG + 4194304;
    float* Vb = BIG + 2 * 4194304;
    float* Ab = BIG + 3 * 4194304;
    float* Hb = BIG;                        // FF hidden aliases Q|K|V|A
    float* x9 = BIG + 16777216;             // 8192
    float* zb = x9 + 8192;                  // 160000

    pos_kernel<<<1024, 256, 0, stream>>>(pos);
    embed_kernel<<<4096, 256, 0, stream>>>(xi, emb, pos, C);

    const float scale = 1.0f / sqrtf(512.0f);
    const dim3 g64_4(64, 4), g64_16(64, 16);

    for (int l = 0; l < NLAYER; ++l) {
        const float* wq = WQ + (size_t)l * 512 * 512;
        const float* wk = WK + (size_t)l * 512 * 512;
        const float* wv = WV + (size_t)l * 512 * 512;
        const float* wo = WO + (size_t)l * 512 * 512;
        const float* w1 = W1 + (size_t)l * 512 * 2048;
        const float* w2 = W2 + (size_t)l * 2048 * 512;

        gemm_f32<true,  EPI_QKV>      <<<g64_4,  256, 0, stream>>>(C,  wq, nullptr,    Qb, N_TOK, 512,  512);
        gemm_f32<true,  EPI_QKV>      <<<g64_4,  256, 0, stream>>>(C,  wk, nullptr,    Kb, N_TOK, 512,  512);
        gemm_f32<true,  EPI_QKV>      <<<g64_4,  256, 0, stream>>>(C,  wv, nullptr,    Vb, N_TOK, 512,  512);
        attn_kernel                   <<<512,    256, 0, stream>>>(Qb, Kb, Vb, ga + l * 8, ba + l * 8, Ab, scale);
        gemm_f32<false, EPI_PLAIN>    <<<g64_4,  256, 0, stream>>>(Ab, wo, nullptr,    PF, N_TOK, 512,  512);
        ln_res_kernel                 <<<2048,   256, 0, stream>>>(PF, C,  g1, be1, l, X2, nullptr);
        gemm_f32<false, EPI_BIAS_RELU><<<g64_16, 256, 0, stream>>>(X2, w1, b1 + l * 2048, Hb, N_TOK, 2048, 512);
        gemm_f32<false, EPI_BIAS>     <<<g64_4,  256, 0, stream>>>(Hb, w2, b2 + l * 512,  PF, N_TOK, 512, 2048);
        ln_res_kernel                 <<<2048,   256, 0, stream>>>(PF, X2, g2, be2, l, OUT, C);
    }

    fin_ve_kernel<<<2048, 256, 0, stream>>>(OUT, Ve, x9);
    fin_vd_kernel<<<157,  256, 0, stream>>>(x9, Vd, zb);
    fin_sm_kernel<<<16,   256, 0, stream>>>(zb, gf, bf, out);
}

// Round 2
// 5050.415 us; speedup vs baseline: 1.8532x; 1.8532x over previous
//
#include <hip/hip_runtime.h>
#include <hip/hip_bf16.h>
#include <math.h>

#define N_TOK 8192
#define DMODEL 512
#define NHEAD 8
#define HDIM 64
#define SEQ 512
#define BATCH 16
#define FFDIM 2048
#define NLAYER 6
#define NCLS 10000

typedef unsigned short u16;
typedef __attribute__((ext_vector_type(8))) short bf16x8;
typedef __attribute__((ext_vector_type(8))) unsigned short u16x8;
typedef __attribute__((ext_vector_type(4))) float f32x4;

__device__ __forceinline__ u16 f2b(float x) {   // RNE f32 -> bf16 (finite inputs)
    unsigned int u = __float_as_uint(x);
    u += 0x7fffu + ((u >> 16) & 1u);
    return (u16)(u >> 16);
}

// ---------------- positional table (fp64 to match np.float64 reference) ------
__global__ __launch_bounds__(256) void pos_kernel(float* __restrict__ pos) {
    const int idx = blockIdx.x * 256 + threadIdx.x;   // 512*512 = 262144
    const int s = idx >> 9, i = idx & 511;
    const double expo = (double)(i & ~1) / 512.0;
    const double ang = (double)s / pow(10000.0, expo);
    pos[idx] = (float)((i & 1) ? cos(ang) : sin(ang));
}

// ---------------- embedding: C = 2*emb[x] + pos ------------------------------
__global__ __launch_bounds__(256) void embed_kernel(const int* __restrict__ xi,
        const float* __restrict__ emb, const float* __restrict__ pos,
        float* __restrict__ C) {
    const int idx = blockIdx.x * 256 + threadIdx.x;   // over N_TOK*128 float4s
    const int n = idx >> 7, d4 = (idx & 127) << 2;
    const int row = xi[n];
    const int s = n & 511;
    const float4 e = *(const float4*)&emb[(size_t)row * 512 + d4];
    const float4 p = *(const float4*)&pos[(size_t)s * 512 + d4];
    float4 o;
    o.x = 2.f * e.x + p.x; o.y = 2.f * e.y + p.y;
    o.z = 2.f * e.z + p.z; o.w = 2.f * e.w + p.w;
    *(float4*)&C[(size_t)n * 512 + d4] = o;
}

// ---------------- f32 tiled GEMM ---------------------------------------------
// C[M,N] = A[M,K] * (BT ? B[N,K]^T : B[K,N]).  128x128 tile, BK=16, 8x8/thread.
enum { EPI_PLAIN = 0, EPI_BIAS_RELU = 1, EPI_BIAS = 2, EPI_QK_B16 = 3, EPI_VT_B16 = 4 };

template<bool BT, int EPI>
__global__ __launch_bounds__(256)
void gemm_f32(const float* __restrict__ A, const float* __restrict__ B,
              const float* __restrict__ bias, float* __restrict__ C,
              int M, int N, int K) {
    __shared__ float As[16][132];
    __shared__ float Bs[16][132];
    const int tid = threadIdx.x;
    const int tx = tid & 15, ty = tid >> 4;
    const int bm = blockIdx.x * 128, bn = blockIdx.y * 128;
    const int ar = tid >> 1, ak = (tid & 1) << 3;
    float acc[8][8] = {};
    for (int k0 = 0; k0 < K; k0 += 16) {
        {   // A tile, transposed into LDS: As[k][m]
            const float4 v0 = *(const float4*)&A[(size_t)(bm + ar) * K + k0 + ak];
            const float4 v1 = *(const float4*)&A[(size_t)(bm + ar) * K + k0 + ak + 4];
            As[ak+0][ar] = v0.x; As[ak+1][ar] = v0.y; As[ak+2][ar] = v0.z; As[ak+3][ar] = v0.w;
            As[ak+4][ar] = v1.x; As[ak+5][ar] = v1.y; As[ak+6][ar] = v1.z; As[ak+7][ar] = v1.w;
        }
        if (BT) {   // B is [N][K] row-major
            const float4 v0 = *(const float4*)&B[(size_t)(bn + ar) * K + k0 + ak];
            const float4 v1 = *(const float4*)&B[(size_t)(bn + ar) * K + k0 + ak + 4];
            Bs[ak+0][ar] = v0.x; Bs[ak+1][ar] = v0.y; Bs[ak+2][ar] = v0.z; Bs[ak+3][ar] = v0.w;
            Bs[ak+4][ar] = v1.x; Bs[ak+5][ar] = v1.y; Bs[ak+6][ar] = v1.z; Bs[ak+7][ar] = v1.w;
        } else {    // B is [K][N] row-major
            const int bk = ty, bnn = tx << 3;
            const float4 v0 = *(const float4*)&B[(size_t)(k0 + bk) * N + bn + bnn];
            const float4 v1 = *(const float4*)&B[(size_t)(k0 + bk) * N + bn + bnn + 4];
            *(float4*)&Bs[bk][bnn]     = v0;
            *(float4*)&Bs[bk][bnn + 4] = v1;
        }
        __syncthreads();
        #pragma unroll
        for (int kk = 0; kk < 16; ++kk) {
            float a[8], b[8];
            *(float4*)&a[0] = *(const float4*)&As[kk][ty << 3];
            *(float4*)&a[4] = *(const float4*)&As[kk][(ty << 3) + 4];
            *(float4*)&b[0] = *(const float4*)&Bs[kk][tx << 3];
            *(float4*)&b[4] = *(const float4*)&Bs[kk][(tx << 3) + 4];
            #pragma unroll
            for (int i = 0; i < 8; ++i)
                #pragma unroll
                for (int j = 0; j < 8; ++j)
                    acc[i][j] = fmaf(a[i], b[j], acc[i][j]);
        }
        __syncthreads();
    }
    if (EPI == EPI_QK_B16) {
        // bf16 head-major: col n -> head n%8, dim n/8 ; out [H][N_TOK][64] bf16
        u16* Cb = (u16*)C;
        #pragma unroll
        for (int i = 0; i < 8; ++i) {
            const int m = bm + (ty << 3) + i;
            #pragma unroll
            for (int j = 0; j < 8; ++j) {
                const int n = bn + (tx << 3) + j;
                Cb[((size_t)(n & 7) * N_TOK + m) * 64 + (n >> 3)] = f2b(acc[i][j]);
            }
        }
    } else if (EPI == EPI_VT_B16) {
        // bf16 transposed V: out [H*B][64][512]; 8 consecutive m = contiguous s
        u16* Cb = (u16*)C;
        const int m0 = bm + (ty << 3);
        const int bb = m0 >> 9, s0 = m0 & 511;
        #pragma unroll
        for (int j = 0; j < 8; ++j) {
            const int n = bn + (tx << 3) + j;
            const int h = n & 7, d = n >> 3;
            u16x8 t;
            #pragma unroll
            for (int i = 0; i < 8; ++i) t[i] = f2b(acc[i][j]);
            *(u16x8*)&Cb[((size_t)(h * 16 + bb) * 64 + d) * 512 + s0] = t;
        }
    } else {
        #pragma unroll
        for (int i = 0; i < 8; ++i) {
            const int m = bm + (ty << 3) + i;
            const int n0 = bn + (tx << 3);
            float vv[8];
            #pragma unroll
            for (int j = 0; j < 8; ++j) {
                float v = acc[i][j];
                if (EPI == EPI_BIAS_RELU) { v += bias[n0 + j]; v = fmaxf(v, 0.f); }
                if (EPI == EPI_BIAS)      { v += bias[n0 + j]; }
                vv[j] = v;
            }
            *(float4*)&C[(size_t)m * N + n0]     = *(float4*)&vv[0];
            *(float4*)&C[(size_t)m * N + n0 + 4] = *(float4*)&vv[4];
        }
    }
}

// ---------------- fused bf16-MFMA attention ----------------------------------
// block = (h, b, qc): 16 q-rows. 4 waves; wave w owns t in [w*128,(w+1)*128)
// for scores, d-cols [w*16,(w+1)*16) for PV. Frags straight from global (L2).
__global__ __launch_bounds__(256)
void attn_mfma(const u16* __restrict__ Qb, const u16* __restrict__ Kb,
               const u16* __restrict__ Vt, const float* __restrict__ ga,
               const float* __restrict__ ba, float* __restrict__ A, float scale) {
    __shared__ __align__(16) u16 al[16 * 536];     // alpha bf16, stride 536 (16B-aligned rows)
    __shared__ float stS[64], stQ[64], stM[64], stE[64];
    const int bid = blockIdx.x;
    const int qc = bid & 31, b = (bid >> 5) & 15, h = bid >> 9;
    const int tid = threadIdx.x, w = tid >> 6, l = tid & 63;
    const int g = l >> 4, c = l & 15;
    const float gah = ga[h], bah = ba[h];
    const size_t qkbase = ((size_t)h * N_TOK + (size_t)b * SEQ) * 64;
    const size_t vtbase = ((size_t)(h * 16 + b)) * 64 * 512;

    // Q A-frags (rows = this block's 16 q-rows; lane row = c, k-slice by g)
    const u16* qrow = Qb + qkbase + (size_t)(qc * 16 + c) * 64;
    const bf16x8 qf0 = *(const bf16x8*)(qrow + g * 8);
    const bf16x8 qf1 = *(const bf16x8*)(qrow + 32 + g * 8);

    // ---- scores: S[16][128] for this wave's t-range, in 8 MFMA tiles --------
    f32x4 acc[8];
    #pragma unroll
    for (int tt = 0; tt < 8; ++tt) {
        const u16* krow = Kb + qkbase + (size_t)(w * 128 + tt * 16 + c) * 64;
        const bf16x8 kf0 = *(const bf16x8*)(krow + g * 8);
        const bf16x8 kf1 = *(const bf16x8*)(krow + 32 + g * 8);
        f32x4 z = {0.f, 0.f, 0.f, 0.f};
        z = __builtin_amdgcn_mfma_f32_16x16x32_bf16(qf0, kf0, z, 0, 0, 0);
        z = __builtin_amdgcn_mfma_f32_16x16x32_bf16(qf1, kf1, z, 0, 0, 0);
        acc[tt] = z;
    }

    // ---- scale + row stats (ddof=1) -----------------------------------------
    // lane holds rows {g*4+r}, t = w*128 + tt*16 + c
    float e[8][4];
    float sm[4] = {0.f,0.f,0.f,0.f}, sq[4] = {0.f,0.f,0.f,0.f};
    #pragma unroll
    for (int tt = 0; tt < 8; ++tt)
        #pragma unroll
        for (int r = 0; r < 4; ++r) {
            const float v = acc[tt][r] * scale;
            e[tt][r] = v; sm[r] += v; sq[r] = fmaf(v, v, sq[r]);
        }
    #pragma unroll
    for (int off = 1; off < 16; off <<= 1)
        #pragma unroll
        for (int r = 0; r < 4; ++r) {
            sm[r] += __shfl_xor(sm[r], off);
            sq[r] += __shfl_xor(sq[r], off);
        }
    if (c == 0) {
        #pragma unroll
        for (int r = 0; r < 4; ++r) { stS[w*16 + g*4 + r] = sm[r]; stQ[w*16 + g*4 + r] = sq[r]; }
    }
    __syncthreads();
    float mu[4], rs[4];
    #pragma unroll
    for (int r = 0; r < 4; ++r) {
        const int rw = g*4 + r;
        const float S  = stS[rw] + stS[16+rw] + stS[32+rw] + stS[48+rw];
        const float Qq = stQ[rw] + stQ[16+rw] + stQ[32+rw] + stQ[48+rw];
        const float m_ = S * (1.f/512.f);
        const float var = (Qq - 512.f * m_ * m_) * (1.f/511.f);
        mu[r] = m_; rs[r] = rsqrtf(var + 1e-8f);
    }
    // ---- normalize + row max -------------------------------------------------
    float mx[4] = {-1e30f,-1e30f,-1e30f,-1e30f};
    #pragma unroll
    for (int tt = 0; tt < 8; ++tt)
        #pragma unroll
        for (int r = 0; r < 4; ++r) {
            const float v = fmaf((e[tt][r] - mu[r]) * rs[r], gah, bah);
            e[tt][r] = v; mx[r] = fmaxf(mx[r], v);
        }
    #pragma unroll
    for (int off = 1; off < 16; off <<= 1)
        #pragma unroll
        for (int r = 0; r < 4; ++r) mx[r] = fmaxf(mx[r], __shfl_xor(mx[r], off));
    if (c == 0) {
        #pragma unroll
        for (int r = 0; r < 4; ++r) stM[w*16 + g*4 + r] = mx[r];
    }
    __syncthreads();
    // ---- exp + row sum ---------------------------------------------------------
    float sme[4] = {0.f,0.f,0.f,0.f};
    #pragma unroll
    for (int r = 0; r < 4; ++r) {
        const int rw = g*4 + r;
        mx[r] = fmaxf(fmaxf(stM[rw], stM[16+rw]), fmaxf(stM[32+rw], stM[48+rw]));
    }
    #pragma unroll
    for (int tt = 0; tt < 8; ++tt)
        #pragma unroll
        for (int r = 0; r < 4; ++r) {
            const float p = expf(e[tt][r] - mx[r]);
            e[tt][r] = p; sme[r] += p;
        }
    #pragma unroll
    for (int off = 1; off < 16; off <<= 1)
        #pragma unroll
        for (int r = 0; r < 4; ++r) sme[r] += __shfl_xor(sme[r], off);
    if (c == 0) {
        #pragma unroll
        for (int r = 0; r < 4; ++r) stE[w*16 + g*4 + r] = sme[r];
    }
    __syncthreads();
    #pragma unroll
    for (int r = 0; r < 4; ++r) {
        const int rw = g*4 + r;
        const float inv = 1.f / (stE[rw] + stE[16+rw] + stE[32+rw] + stE[48+rw]);
        #pragma unroll
        for (int tt = 0; tt < 8; ++tt)
            al[(size_t)(g*4 + r) * 536 + w*128 + tt*16 + c] = f2b(e[tt][r] * inv);
    }
    __syncthreads();

    // ---- PV: out[16][16] per wave at d0 = w*16 --------------------------------
    f32x4 o = {0.f, 0.f, 0.f, 0.f};
    #pragma unroll
    for (int ks = 0; ks < 16; ++ks) {
        const bf16x8 af = *(const bf16x8*)&al[(size_t)c * 536 + ks*32 + g*8];
        const bf16x8 vf = *(const bf16x8*)(Vt + vtbase + (size_t)(w*16 + c) * 512 + ks*32 + g*8);
        o = __builtin_amdgcn_mfma_f32_16x16x32_bf16(af, vf, o, 0, 0, 0);
    }
    #pragma unroll
    for (int r = 0; r < 4; ++r)
        A[((size_t)(b * 512 + qc * 16 + g*4 + r)) * 512 + h * 64 + w*16 + c] = o[r];
}

// ---------------- LayerNorm(X + R) with scalar gamma/beta; optional C += y ----
__global__ __launch_bounds__(256)
void ln_res_kernel(const float* __restrict__ X, const float* __restrict__ R,
                   const float* __restrict__ gp, const float* __restrict__ bp,
                   int lidx, float* __restrict__ Y, float* __restrict__ Cacc) {
    const int tid = threadIdx.x, w = tid >> 6, l = tid & 63;
    const size_t row = (size_t)blockIdx.x * 4 + w;
    const float g = gp[lidx], bb = bp[lidx];
    const float* x = X + row * 512;
    const float* r = R + row * 512;
    float v[8];
    const float4 a0 = *(const float4*)&x[l * 8], a1 = *(const float4*)&x[l * 8 + 4];
    const float4 r0 = *(const float4*)&r[l * 8], r1 = *(const float4*)&r[l * 8 + 4];
    v[0] = a0.x + r0.x; v[1] = a0.y + r0.y; v[2] = a0.z + r0.z; v[3] = a0.w + r0.w;
    v[4] = a1.x + r1.x; v[5] = a1.y + r1.y; v[6] = a1.z + r1.z; v[7] = a1.w + r1.w;
    float s = 0.f, sq = 0.f;
    #pragma unroll
    for (int i = 0; i < 8; ++i) { s += v[i]; sq = fmaf(v[i], v[i], sq); }
    #pragma unroll
    for (int o = 1; o < 64; o <<= 1) { s += __shfl_xor(s, o); sq += __shfl_xor(sq, o); }
    const float mu   = s * (1.f / 512.f);
    const float var  = (sq - 512.f * mu * mu) * (1.f / 511.f);
    const float rstd = rsqrtf(var + 1e-8f);
    float y[8];
    #pragma unroll
    for (int i = 0; i < 8; ++i) y[i] = fmaf((v[i] - mu) * rstd, g, bb);
    *(float4*)&Y[row * 512 + l * 8]     = *(float4*)&y[0];
    *(float4*)&Y[row * 512 + l * 8 + 4] = *(float4*)&y[4];
    if (Cacc) {
        float4 c0 = *(float4*)&Cacc[row * 512 + l * 8];
        float4 c1 = *(float4*)&Cacc[row * 512 + l * 8 + 4];
        c0.x += y[0]; c0.y += y[1]; c0.z += y[2]; c0.w += y[3];
        c1.x += y[4]; c1.y += y[5]; c1.z += y[6]; c1.w += y[7];
        *(float4*)&Cacc[row * 512 + l * 8]     = c0;
        *(float4*)&Cacc[row * 512 + l * 8 + 4] = c1;
    }
}

// ---------------- final head: x9 = X8 @ V_e ----------------------------------
__global__ __launch_bounds__(256)
void fin_ve_kernel(const float* __restrict__ X8, const float* __restrict__ Ve,
                   float* __restrict__ x9) {
    const int tid = threadIdx.x, w = tid >> 6, l = tid & 63;
    const size_t row = (size_t)blockIdx.x * 4 + w;
    const float* x = X8 + row * 512;
    float s = 0.f;
    #pragma unroll
    for (int i = 0; i < 8; ++i) s = fmaf(x[l * 8 + i], Ve[l * 8 + i], s);
    #pragma unroll
    for (int o = 1; o < 64; o <<= 1) s += __shfl_xor(s, o);
    if (l == 0) x9[row] = s;
}

// ---------------- z[b,c] = sum_s x9[b,s] * Vd[s,c] ---------------------------
__global__ __launch_bounds__(256)
void fin_vd_kernel(const float* __restrict__ x9, const float* __restrict__ Vd,
                   float* __restrict__ z) {
    __shared__ float red[4][16][65];
    const int tid = threadIdx.x, l = tid & 63, sch = tid >> 6;
    const int c = blockIdx.x * 64 + l;
    float acc[16];
    #pragma unroll
    for (int b = 0; b < 16; ++b) acc[b] = 0.f;
    if (c < NCLS) {
        for (int s = sch * 128; s < sch * 128 + 128; ++s) {
            const float vd = Vd[(size_t)s * NCLS + c];
            #pragma unroll
            for (int b = 0; b < 16; ++b) acc[b] = fmaf(x9[b * 512 + s], vd, acc[b]);
        }
    }
    #pragma unroll
    for (int b = 0; b < 16; ++b) red[sch][b][l] = acc[b];
    __syncthreads();
    if (sch == 0 && c < NCLS) {
        #pragma unroll
        for (int b = 0; b < 16; ++b)
            z[(size_t)b * NCLS + c] = red[0][b][l] + red[1][b][l] + red[2][b][l] + red[3][b][l];
    }
}

// ---------------- final norm (ddof=1 over 10000) + softmax -------------------
__global__ __launch_bounds__(256)
void fin_sm_kernel(const float* __restrict__ z, const float* __restrict__ gp,
                   const float* __restrict__ bp, float* __restrict__ out) {
    __shared__ float zs[NCLS];
    __shared__ float red[4];
    __shared__ float red2[4];
    const int b = blockIdx.x, tid = threadIdx.x, w = tid >> 6, l = tid & 63;
    float s = 0.f, sq = 0.f;
    for (int i = tid; i < NCLS; i += 256) {
        const float v = z[(size_t)b * NCLS + i];
        zs[i] = v; s += v; sq = fmaf(v, v, sq);
    }
    #pragma unroll
    for (int o = 1; o < 64; o <<= 1) { s += __shfl_xor(s, o); sq += __shfl_xor(sq, o); }
    if (l == 0) { red[w] = s; red2[w] = sq; }
    __syncthreads();
    s  = red[0] + red[1] + red[2] + red[3];
    sq = red2[0] + red2[1] + red2[2] + red2[3];
    const float mu   = s / 10000.f;
    const float var  = (sq - 10000.f * mu * mu) / 9999.f;
    const float rstd = rsqrtf(var + 1e-8f);
    const float g = gp[0], be = bp[0];
    __syncthreads();
    float mx = -1e30f;
    for (int i = tid; i < NCLS; i += 256) {
        const float e = fmaf((zs[i] - mu) * rstd, g, be);
        zs[i] = e; mx = fmaxf(mx, e);
    }
    #pragma unroll
    for (int o = 1; o < 64; o <<= 1) mx = fmaxf(mx, __shfl_xor(mx, o));
    if (l == 0) red[w] = mx;
    __syncthreads();
    mx = fmaxf(fmaxf(red[0], red[1]), fmaxf(red[2], red[3]));
    float es = 0.f;
    for (int i = tid; i < NCLS; i += 256) {
        const float p = expf(zs[i] - mx);
        zs[i] = p; es += p;
    }
    #pragma unroll
    for (int o = 1; o < 64; o <<= 1) es += __shfl_xor(es, o);
    if (l == 0) red2[w] = es;
    __syncthreads();
    es = red2[0] + red2[1] + red2[2] + red2[3];
    const float inv = 1.f / es;
    for (int i = tid; i < NCLS; i += 256) out[(size_t)b * NCLS + i] = zs[i] * inv;
}

// =============================================================================
extern "C" void kernel_launch(void* const* d_in, const int* in_sizes, int n_in,
                              void* d_out, int out_size, void* d_ws, size_t ws_size,
                              hipStream_t stream) {
    (void)in_sizes; (void)n_in; (void)out_size; (void)ws_size;
    const int*   xi  = (const int*)d_in[0];
    const float* emb = (const float*)d_in[1];
    const float* WQ  = (const float*)d_in[2];
    const float* WK  = (const float*)d_in[3];
    const float* WV  = (const float*)d_in[4];
    const float* WO  = (const float*)d_in[5];
    const float* W1  = (const float*)d_in[6];
    const float* b1  = (const float*)d_in[7];
    const float* W2  = (const float*)d_in[8];
    const float* b2  = (const float*)d_in[9];
    const float* ga  = (const float*)d_in[10];
    const float* ba  = (const float*)d_in[11];
    const float* g1  = (const float*)d_in[12];
    const float* be1 = (const float*)d_in[13];
    const float* g2  = (const float*)d_in[14];
    const float* be2 = (const float*)d_in[15];
    const float* Ve  = (const float*)d_in[16];
    const float* Vd  = (const float*)d_in[17];
    const float* gf  = (const float*)d_in[18];
    const float* bf  = (const float*)d_in[19];
    float* out = (float*)d_out;

    // workspace layout (floats)
    float* ws  = (float*)d_ws;
    float* pos = ws;                        // 262144
    float* C   = pos + 262144;              // 4M floats each below
    float* X2  = C   + 4194304;
    float* OUT = X2  + 4194304;
    float* PF  = OUT + 4194304;
    float* BIG = PF  + 4194304;             // 16777216 floats
    float* Ab  = BIG;                               // f32 [8192][512]
    u16*  Qbf  = (u16*)(BIG + 4194304);             // bf16 [H][8192][64]
    u16*  Kbf  = (u16*)(BIG + 4194304 + 2097152);   // bf16 [H][8192][64]
    u16*  Vtb  = (u16*)(BIG + 4194304 + 2*2097152); // bf16 [H*B][64][512]
    float* Hb  = BIG;                       // FF hidden aliases attn buffers
    float* x9  = BIG + 16777216;            // 8192
    float* zb  = x9 + 8192;                 // 160000

    pos_kernel<<<1024, 256, 0, stream>>>(pos);
    embed_kernel<<<4096, 256, 0, stream>>>(xi, emb, pos, C);

    const float scale = 1.0f / sqrtf(512.0f);
    const dim3 g64_4(64, 4), g64_16(64, 16);

    for (int l = 0; l < NLAYER; ++l) {
        const float* wq = WQ + (size_t)l * 512 * 512;
        const float* wk = WK + (size_t)l * 512 * 512;
        const float* wv = WV + (size_t)l * 512 * 512;
        const float* wo = WO + (size_t)l * 512 * 512;
        const float* w1 = W1 + (size_t)l * 512 * 2048;
        const float* w2 = W2 + (size_t)l * 2048 * 512;

        gemm_f32<true,  EPI_QK_B16>   <<<g64_4,  256, 0, stream>>>(C,  wq, nullptr, (float*)Qbf, N_TOK, 512,  512);
        gemm_f32<true,  EPI_QK_B16>   <<<g64_4,  256, 0, stream>>>(C,  wk, nullptr, (float*)Kbf, N_TOK, 512,  512);
        gemm_f32<true,  EPI_VT_B16>   <<<g64_4,  256, 0, stream>>>(C,  wv, nullptr, (float*)Vtb, N_TOK, 512,  512);
        attn_mfma                     <<<4096,   256, 0, stream>>>(Qbf, Kbf, Vtb, ga + l * 8, ba + l * 8, Ab, scale);
        gemm_f32<false, EPI_PLAIN>    <<<g64_4,  256, 0, stream>>>(Ab, wo, nullptr,    PF, N_TOK, 512,  512);
        ln_res_kernel                 <<<2048,   256, 0, stream>>>(PF, C,  g1, be1, l, X2, nullptr);
        gemm_f32<false, EPI_BIAS_RELU><<<g64_16, 256, 0, stream>>>(X2, w1, b1 + l * 2048, Hb, N_TOK, 2048, 512);
        gemm_f32<false, EPI_BIAS>     <<<g64_4,  256, 0, stream>>>(Hb, w2, b2 + l * 512,  PF, N_TOK, 512, 2048);
        ln_res_kernel                 <<<2048,   256, 0, stream>>>(PF, X2, g2, be2, l, OUT, C);
    }

    fin_ve_kernel<<<2048, 256, 0, stream>>>(OUT, Ve, x9);
    fin_vd_kernel<<<157,  256, 0, stream>>>(x9, Vd, zb);
    fin_sm_kernel<<<16,   256, 0, stream>>>(zb, gf, bf, out);
}

// Round 3
// 1497.147 us; speedup vs baseline: 6.2513x; 3.3734x over previous
//
#include <hip/hip_runtime.h>
#include <hip/hip_bf16.h>
#include <math.h>

#define N_TOK 8192
#define DMODEL 512
#define NHEAD 8
#define HDIM 64
#define SEQ 512
#define BATCH 16
#define FFDIM 2048
#define NLAYER 6
#define NCLS 10000

typedef unsigned short u16;
typedef __attribute__((ext_vector_type(8))) short bf16x8;
typedef __attribute__((ext_vector_type(8))) unsigned short u16x8;
typedef __attribute__((ext_vector_type(4))) unsigned short u16x4;
typedef __attribute__((ext_vector_type(4))) float f32x4;

__device__ __forceinline__ u16 f2b(float x) {   // RNE f32 -> bf16 (finite inputs)
    unsigned int u = __float_as_uint(x);
    u += 0x7fffu + ((u >> 16) & 1u);
    return (u16)(u >> 16);
}

__device__ __forceinline__ void gl_lds16(const void* g, void* l) {
    __builtin_amdgcn_global_load_lds(
        (const __attribute__((address_space(1))) unsigned int*)g,
        (__attribute__((address_space(3))) unsigned int*)l, 16, 0, 0);
}

// ---------------- positional table (fp64 to match np.float64 reference) ------
__global__ __launch_bounds__(256) void pos_kernel(float* __restrict__ pos) {
    const int idx = blockIdx.x * 256 + threadIdx.x;   // 512*512 = 262144
    const int s = idx >> 9, i = idx & 511;
    const double expo = (double)(i & ~1) / 512.0;
    const double ang = (double)s / pow(10000.0, expo);
    pos[idx] = (float)((i & 1) ? cos(ang) : sin(ang));
}

// ---------------- embedding: C = 2*emb[x] + pos (f32 + bf16 copies) ----------
__global__ __launch_bounds__(256) void embed_kernel(const int* __restrict__ xi,
        const float* __restrict__ emb, const float* __restrict__ pos,
        float* __restrict__ C, u16* __restrict__ Cb) {
    const int idx = blockIdx.x * 256 + threadIdx.x;   // over N_TOK*128 float4s
    const int n = idx >> 7, d4 = (idx & 127) << 2;
    const int row = xi[n];
    const int s = n & 511;
    const float4 e = *(const float4*)&emb[(size_t)row * 512 + d4];
    const float4 p = *(const float4*)&pos[(size_t)s * 512 + d4];
    float4 o;
    o.x = 2.f * e.x + p.x; o.y = 2.f * e.y + p.y;
    o.z = 2.f * e.z + p.z; o.w = 2.f * e.w + p.w;
    *(float4*)&C[(size_t)n * 512 + d4] = o;
    u16x4 ob = { f2b(o.x), f2b(o.y), f2b(o.z), f2b(o.w) };
    *(u16x4*)&Cb[(size_t)n * 512 + d4] = ob;
}

// ---------------- weight converts --------------------------------------------
__global__ __launch_bounds__(256) void cvt_b16_kernel(const float* __restrict__ src,
        u16* __restrict__ dst, int n4) {
    const int i = blockIdx.x * 256 + threadIdx.x;
    if (i < n4) {
        const float4 v = ((const float4*)src)[i];
        u16x4 o = { f2b(v.x), f2b(v.y), f2b(v.z), f2b(v.w) };
        *(u16x4*)&dst[(size_t)i * 4] = o;
    }
}

// src [Kd][Nd] f32 per layer (z) -> dst [Nd][Kd] bf16
__global__ __launch_bounds__(256) void tcvt_b16_kernel(const float* __restrict__ src,
        u16* __restrict__ dst, int Kd, int Nd) {
    __shared__ u16 t[64][65];
    const int k0 = blockIdx.x * 64, n0 = blockIdx.y * 64;
    const size_t off = (size_t)blockIdx.z * Kd * Nd;
    src += off; dst += off;
    const int cx = threadIdx.x & 63, r0 = threadIdx.x >> 6;
    #pragma unroll
    for (int i = 0; i < 16; ++i) {
        const int r = r0 * 16 + i;
        t[cx][r] = f2b(src[(size_t)(k0 + r) * Nd + n0 + cx]);
    }
    __syncthreads();
    #pragma unroll
    for (int i = 0; i < 16; ++i) {
        const int nn = r0 * 16 + i;
        dst[(size_t)(n0 + nn) * Kd + k0 + cx] = t[nn][cx];
    }
}

// ---------------- bf16 MFMA GEMM: C = A[8192,K] * Bt[N,K]^T -------------------
// 128x128 tile, BK=64, 4 waves (2x2), 4x4 16x16x32 frags/wave.
// global_load_lds w/ source-swizzle; frag ds_read_b128 XOR-swizzled (T2).
enum { EG_QK = 0, EG_VT = 1, EG_F32 = 2, EG_BIAS_F32 = 3, EG_BRELU_B16 = 4 };

template<int EPI>
__global__ __launch_bounds__(256)
void gemm_bf16(const u16* __restrict__ A, const u16* __restrict__ Bt,
               const float* __restrict__ bias, void* __restrict__ Cout,
               int N, int K) {
    __shared__ u16 As[128 * 64];
    __shared__ u16 Bs[128 * 64];
    const int tid = threadIdx.x, w = tid >> 6, l = tid & 63;
    const int g = l >> 4, c = l & 15;
    const int wm = w >> 1, wn = w & 1;
    const int bm = blockIdx.x * 128, bn = blockIdx.y * 128;
    const int sr = l >> 3, sc8 = l & 7;

    const f32x4 zero = {0.f, 0.f, 0.f, 0.f};
    f32x4 acc[4][4];
    #pragma unroll
    for (int i = 0; i < 4; ++i)
        #pragma unroll
        for (int j = 0; j < 4; ++j) acc[i][j] = zero;

    for (int k0 = 0; k0 < K; k0 += 64) {
        __syncthreads();
        #pragma unroll
        for (int i = 0; i < 4; ++i) {
            const int rb = w * 32 + i * 8;
            const int r = rb + sr;
            const int ck = (sc8 ^ (r & 7)) * 8;   // source pre-swizzle (involution)
            gl_lds16(A  + (size_t)(bm + r) * K + k0 + ck, &As[rb * 64]);
            gl_lds16(Bt + (size_t)(bn + r) * K + k0 + ck, &Bs[rb * 64]);
        }
        __syncthreads();
        #pragma unroll
        for (int ks = 0; ks < 2; ++ks) {
            bf16x8 af[4], bfv[4];
            #pragma unroll
            for (int q = 0; q < 4; ++q) {
                const int ra = wm * 64 + q * 16 + c;
                af[q] = *(const bf16x8*)((const char*)As +
                        ((ra * 128 + ks * 64 + g * 16) ^ ((ra & 7) << 4)));
                const int rb2 = wn * 64 + q * 16 + c;
                bfv[q] = *(const bf16x8*)((const char*)Bs +
                        ((rb2 * 128 + ks * 64 + g * 16) ^ ((rb2 & 7) << 4)));
            }
            #pragma unroll
            for (int mf = 0; mf < 4; ++mf)
                #pragma unroll
                for (int nf = 0; nf < 4; ++nf)
                    acc[mf][nf] = __builtin_amdgcn_mfma_f32_16x16x32_bf16(
                        af[mf], bfv[nf], acc[mf][nf], 0, 0, 0);
        }
    }

    #pragma unroll
    for (int mf = 0; mf < 4; ++mf) {
        #pragma unroll
        for (int nf = 0; nf < 4; ++nf) {
            const int n  = bn + wn * 64 + nf * 16 + c;
            const int m0 = bm + wm * 64 + mf * 16 + g * 4;
            if (EPI == EG_QK) {
                u16* o = (u16*)Cout;
                const size_t b0 = (size_t)(n & 7) * N_TOK * 64 + (n >> 3);
                #pragma unroll
                for (int r = 0; r < 4; ++r)
                    o[b0 + (size_t)(m0 + r) * 64] = f2b(acc[mf][nf][r]);
            } else if (EPI == EG_VT) {
                u16* o = (u16*)Cout;
                const int h = n & 7, d = n >> 3, bb = m0 >> 9, s0 = m0 & 511;
                u16x4 pk = { f2b(acc[mf][nf][0]), f2b(acc[mf][nf][1]),
                             f2b(acc[mf][nf][2]), f2b(acc[mf][nf][3]) };
                *(u16x4*)&o[((size_t)(h * 16 + bb) * 64 + d) * 512 + s0] = pk;
            } else if (EPI == EG_F32) {
                float* o = (float*)Cout;
                #pragma unroll
                for (int r = 0; r < 4; ++r)
                    o[(size_t)(m0 + r) * N + n] = acc[mf][nf][r];
            } else if (EPI == EG_BIAS_F32) {
                float* o = (float*)Cout;
                const float bv = bias[n];
                #pragma unroll
                for (int r = 0; r < 4; ++r)
                    o[(size_t)(m0 + r) * N + n] = acc[mf][nf][r] + bv;
            } else {  // EG_BRELU_B16
                u16* o = (u16*)Cout;
                const float bv = bias[n];
                #pragma unroll
                for (int r = 0; r < 4; ++r)
                    o[(size_t)(m0 + r) * N + n] = f2b(fmaxf(acc[mf][nf][r] + bv, 0.f));
            }
        }
    }
}

// ---------------- fused bf16-MFMA attention (out -> bf16) --------------------
__global__ __launch_bounds__(256)
void attn_mfma(const u16* __restrict__ Qb, const u16* __restrict__ Kb,
               const u16* __restrict__ Vt, const float* __restrict__ ga,
               const float* __restrict__ ba, u16* __restrict__ A, float scale) {
    __shared__ __align__(16) u16 al[16 * 536];
    __shared__ float stS[64], stQ[64], stM[64], stE[64];
    const int bid = blockIdx.x;
    const int qc = bid & 31, b = (bid >> 5) & 15, h = bid >> 9;
    const int tid = threadIdx.x, w = tid >> 6, l = tid & 63;
    const int g = l >> 4, c = l & 15;
    const float gah = ga[h], bah = ba[h];
    const size_t qkbase = ((size_t)h * N_TOK + (size_t)b * SEQ) * 64;
    const size_t vtbase = ((size_t)(h * 16 + b)) * 64 * 512;

    const u16* qrow = Qb + qkbase + (size_t)(qc * 16 + c) * 64;
    const bf16x8 qf0 = *(const bf16x8*)(qrow + g * 8);
    const bf16x8 qf1 = *(const bf16x8*)(qrow + 32 + g * 8);

    f32x4 acc[8];
    #pragma unroll
    for (int tt = 0; tt < 8; ++tt) {
        const u16* krow = Kb + qkbase + (size_t)(w * 128 + tt * 16 + c) * 64;
        const bf16x8 kf0 = *(const bf16x8*)(krow + g * 8);
        const bf16x8 kf1 = *(const bf16x8*)(krow + 32 + g * 8);
        f32x4 z = {0.f, 0.f, 0.f, 0.f};
        z = __builtin_amdgcn_mfma_f32_16x16x32_bf16(qf0, kf0, z, 0, 0, 0);
        z = __builtin_amdgcn_mfma_f32_16x16x32_bf16(qf1, kf1, z, 0, 0, 0);
        acc[tt] = z;
    }

    float e[8][4];
    float sm[4] = {0.f,0.f,0.f,0.f}, sq[4] = {0.f,0.f,0.f,0.f};
    #pragma unroll
    for (int tt = 0; tt < 8; ++tt)
        #pragma unroll
        for (int r = 0; r < 4; ++r) {
            const float v = acc[tt][r] * scale;
            e[tt][r] = v; sm[r] += v; sq[r] = fmaf(v, v, sq[r]);
        }
    #pragma unroll
    for (int off = 1; off < 16; off <<= 1)
        #pragma unroll
        for (int r = 0; r < 4; ++r) {
            sm[r] += __shfl_xor(sm[r], off);
            sq[r] += __shfl_xor(sq[r], off);
        }
    if (c == 0) {
        #pragma unroll
        for (int r = 0; r < 4; ++r) { stS[w*16 + g*4 + r] = sm[r]; stQ[w*16 + g*4 + r] = sq[r]; }
    }
    __syncthreads();
    float mu[4], rs[4];
    #pragma unroll
    for (int r = 0; r < 4; ++r) {
        const int rw = g*4 + r;
        const float S  = stS[rw] + stS[16+rw] + stS[32+rw] + stS[48+rw];
        const float Qq = stQ[rw] + stQ[16+rw] + stQ[32+rw] + stQ[48+rw];
        const float m_ = S * (1.f/512.f);
        const float var = (Qq - 512.f * m_ * m_) * (1.f/511.f);
        mu[r] = m_; rs[r] = rsqrtf(var + 1e-8f);
    }
    float mx[4] = {-1e30f,-1e30f,-1e30f,-1e30f};
    #pragma unroll
    for (int tt = 0; tt < 8; ++tt)
        #pragma unroll
        for (int r = 0; r < 4; ++r) {
            const float v = fmaf((e[tt][r] - mu[r]) * rs[r], gah, bah);
            e[tt][r] = v; mx[r] = fmaxf(mx[r], v);
        }
    #pragma unroll
    for (int off = 1; off < 16; off <<= 1)
        #pragma unroll
        for (int r = 0; r < 4; ++r) mx[r] = fmaxf(mx[r], __shfl_xor(mx[r], off));
    if (c == 0) {
        #pragma unroll
        for (int r = 0; r < 4; ++r) stM[w*16 + g*4 + r] = mx[r];
    }
    __syncthreads();
    float sme[4] = {0.f,0.f,0.f,0.f};
    #pragma unroll
    for (int r = 0; r < 4; ++r) {
        const int rw = g*4 + r;
        mx[r] = fmaxf(fmaxf(stM[rw], stM[16+rw]), fmaxf(stM[32+rw], stM[48+rw]));
    }
    #pragma unroll
    for (int tt = 0; tt < 8; ++tt)
        #pragma unroll
        for (int r = 0; r < 4; ++r) {
            const float p = expf(e[tt][r] - mx[r]);
            e[tt][r] = p; sme[r] += p;
        }
    #pragma unroll
    for (int off = 1; off < 16; off <<= 1)
        #pragma unroll
        for (int r = 0; r < 4; ++r) sme[r] += __shfl_xor(sme[r], off);
    if (c == 0) {
        #pragma unroll
        for (int r = 0; r < 4; ++r) stE[w*16 + g*4 + r] = sme[r];
    }
    __syncthreads();
    #pragma unroll
    for (int r = 0; r < 4; ++r) {
        const int rw = g*4 + r;
        const float inv = 1.f / (stE[rw] + stE[16+rw] + stE[32+rw] + stE[48+rw]);
        #pragma unroll
        for (int tt = 0; tt < 8; ++tt)
            al[(size_t)(g*4 + r) * 536 + w*128 + tt*16 + c] = f2b(e[tt][r] * inv);
    }
    __syncthreads();

    f32x4 o = {0.f, 0.f, 0.f, 0.f};
    #pragma unroll
    for (int ks = 0; ks < 16; ++ks) {
        const bf16x8 af = *(const bf16x8*)&al[(size_t)c * 536 + ks*32 + g*8];
        const bf16x8 vf = *(const bf16x8*)(Vt + vtbase + (size_t)(w*16 + c) * 512 + ks*32 + g*8);
        o = __builtin_amdgcn_mfma_f32_16x16x32_bf16(af, vf, o, 0, 0, 0);
    }
    #pragma unroll
    for (int r = 0; r < 4; ++r)
        A[((size_t)(b * 512 + qc * 16 + g*4 + r)) * 512 + h * 64 + w*16 + c] = f2b(o[r]);
}

// ---------------- LayerNorm(X + R); optional bf16 copy, carry accumulate -----
__global__ __launch_bounds__(256)
void ln_res_kernel(const float* __restrict__ X, const float* __restrict__ R,
                   const float* __restrict__ gp, const float* __restrict__ bp,
                   int lidx, float* __restrict__ Y, u16* __restrict__ Yb,
                   float* __restrict__ Cacc, u16* __restrict__ Cb) {
    const int tid = threadIdx.x, w = tid >> 6, l = tid & 63;
    const size_t row = (size_t)blockIdx.x * 4 + w;
    const float g = gp[lidx], bb = bp[lidx];
    const float* x = X + row * 512;
    const float* r = R + row * 512;
    float v[8];
    const float4 a0 = *(const float4*)&x[l * 8], a1 = *(const float4*)&x[l * 8 + 4];
    const float4 r0 = *(const float4*)&r[l * 8], r1 = *(const float4*)&r[l * 8 + 4];
    v[0] = a0.x + r0.x; v[1] = a0.y + r0.y; v[2] = a0.z + r0.z; v[3] = a0.w + r0.w;
    v[4] = a1.x + r1.x; v[5] = a1.y + r1.y; v[6] = a1.z + r1.z; v[7] = a1.w + r1.w;
    float s = 0.f, sq = 0.f;
    #pragma unroll
    for (int i = 0; i < 8; ++i) { s += v[i]; sq = fmaf(v[i], v[i], sq); }
    #pragma unroll
    for (int o = 1; o < 64; o <<= 1) { s += __shfl_xor(s, o); sq += __shfl_xor(sq, o); }
    const float mu   = s * (1.f / 512.f);
    const float var  = (sq - 512.f * mu * mu) * (1.f / 511.f);
    const float rstd = rsqrtf(var + 1e-8f);
    float y[8];
    #pragma unroll
    for (int i = 0; i < 8; ++i) y[i] = fmaf((v[i] - mu) * rstd, g, bb);
    *(float4*)&Y[row * 512 + l * 8]     = *(float4*)&y[0];
    *(float4*)&Y[row * 512 + l * 8 + 4] = *(float4*)&y[4];
    if (Yb) {
        u16x8 yb;
        #pragma unroll
        for (int i = 0; i < 8; ++i) yb[i] = f2b(y[i]);
        *(u16x8*)&Yb[row * 512 + l * 8] = yb;
    }
    if (Cacc) {
        float cv[8];
        float4 c0 = *(float4*)&Cacc[row * 512 + l * 8];
        float4 c1 = *(float4*)&Cacc[row * 512 + l * 8 + 4];
        cv[0] = c0.x + y[0]; cv[1] = c0.y + y[1]; cv[2] = c0.z + y[2]; cv[3] = c0.w + y[3];
        cv[4] = c1.x + y[4]; cv[5] = c1.y + y[5]; cv[6] = c1.z + y[6]; cv[7] = c1.w + y[7];
        *(float4*)&Cacc[row * 512 + l * 8]     = *(float4*)&cv[0];
        *(float4*)&Cacc[row * 512 + l * 8 + 4] = *(float4*)&cv[4];
        u16x8 cb;
        #pragma unroll
        for (int i = 0; i < 8; ++i) cb[i] = f2b(cv[i]);
        *(u16x8*)&Cb[row * 512 + l * 8] = cb;
    }
}

// ---------------- final head: x9 = X8 @ V_e ----------------------------------
__global__ __launch_bounds__(256)
void fin_ve_kernel(const float* __restrict__ X8, const float* __restrict__ Ve,
                   float* __restrict__ x9) {
    const int tid = threadIdx.x, w = tid >> 6, l = tid & 63;
    const size_t row = (size_t)blockIdx.x * 4 + w;
    const float* x = X8 + row * 512;
    float s = 0.f;
    #pragma unroll
    for (int i = 0; i < 8; ++i) s = fmaf(x[l * 8 + i], Ve[l * 8 + i], s);
    #pragma unroll
    for (int o = 1; o < 64; o <<= 1) s += __shfl_xor(s, o);
    if (l == 0) x9[row] = s;
}

// ---------------- z[b,c] = sum_s x9[b,s] * Vd[s,c] ---------------------------
__global__ __launch_bounds__(256)
void fin_vd_kernel(const float* __restrict__ x9, const float* __restrict__ Vd,
                   float* __restrict__ z) {
    __shared__ float red[4][16][65];
    const int tid = threadIdx.x, l = tid & 63, sch = tid >> 6;
    const int c = blockIdx.x * 64 + l;
    float acc[16];
    #pragma unroll
    for (int b = 0; b < 16; ++b) acc[b] = 0.f;
    if (c < NCLS) {
        for (int s = sch * 128; s < sch * 128 + 128; ++s) {
            const float vd = Vd[(size_t)s * NCLS + c];
            #pragma unroll
            for (int b = 0; b < 16; ++b) acc[b] = fmaf(x9[b * 512 + s], vd, acc[b]);
        }
    }
    #pragma unroll
    for (int b = 0; b < 16; ++b) red[sch][b][l] = acc[b];
    __syncthreads();
    if (sch == 0 && c < NCLS) {
        #pragma unroll
        for (int b = 0; b < 16; ++b)
            z[(size_t)b * NCLS + c] = red[0][b][l] + red[1][b][l] + red[2][b][l] + red[3][b][l];
    }
}

// ---------------- final norm (ddof=1 over 10000) + softmax -------------------
__global__ __launch_bounds__(256)
void fin_sm_kernel(const float* __restrict__ z, const float* __restrict__ gp,
                   const float* __restrict__ bp, float* __restrict__ out) {
    __shared__ float zs[NCLS];
    __shared__ float red[4];
    __shared__ float red2[4];
    const int b = blockIdx.x, tid = threadIdx.x, w = tid >> 6, l = tid & 63;
    float s = 0.f, sq = 0.f;
    for (int i = tid; i < NCLS; i += 256) {
        const float v = z[(size_t)b * NCLS + i];
        zs[i] = v; s += v; sq = fmaf(v, v, sq);
    }
    #pragma unroll
    for (int o = 1; o < 64; o <<= 1) { s += __shfl_xor(s, o); sq += __shfl_xor(sq, o); }
    if (l == 0) { red[w] = s; red2[w] = sq; }
    __syncthreads();
    s  = red[0] + red[1] + red[2] + red[3];
    sq = red2[0] + red2[1] + red2[2] + red2[3];
    const float mu   = s / 10000.f;
    const float var  = (sq - 10000.f * mu * mu) / 9999.f;
    const float rstd = rsqrtf(var + 1e-8f);
    const float g = gp[0], be = bp[0];
    __syncthreads();
    float mx = -1e30f;
    for (int i = tid; i < NCLS; i += 256) {
        const float e = fmaf((zs[i] - mu) * rstd, g, be);
        zs[i] = e; mx = fmaxf(mx, e);
    }
    #pragma unroll
    for (int o = 1; o < 64; o <<= 1) mx = fmaxf(mx, __shfl_xor(mx, o));
    if (l == 0) red[w] = mx;
    __syncthreads();
    mx = fmaxf(fmaxf(red[0], red[1]), fmaxf(red[2], red[3]));
    float es = 0.f;
    for (int i = tid; i < NCLS; i += 256) {
        const float p = expf(zs[i] - mx);
        zs[i] = p; es += p;
    }
    #pragma unroll
    for (int o = 1; o < 64; o <<= 1) es += __shfl_xor(es, o);
    if (l == 0) red2[w] = es;
    __syncthreads();
    es = red2[0] + red2[1] + red2[2] + red2[3];
    const float inv = 1.f / es;
    for (int i = tid; i < NCLS; i += 256) out[(size_t)b * NCLS + i] = zs[i] * inv;
}

// =============================================================================
extern "C" void kernel_launch(void* const* d_in, const int* in_sizes, int n_in,
                              void* d_out, int out_size, void* d_ws, size_t ws_size,
                              hipStream_t stream) {
    (void)in_sizes; (void)n_in; (void)out_size; (void)ws_size;
    const int*   xi  = (const int*)d_in[0];
    const float* emb = (const float*)d_in[1];
    const float* WQ  = (const float*)d_in[2];
    const float* WK  = (const float*)d_in[3];
    const float* WV  = (const float*)d_in[4];
    const float* WO  = (const float*)d_in[5];
    const float* W1  = (const float*)d_in[6];
    const float* b1  = (const float*)d_in[7];
    const float* W2  = (const float*)d_in[8];
    const float* b2  = (const float*)d_in[9];
    const float* ga  = (const float*)d_in[10];
    const float* ba  = (const float*)d_in[11];
    const float* g1  = (const float*)d_in[12];
    const float* be1 = (const float*)d_in[13];
    const float* g2  = (const float*)d_in[14];
    const float* be2 = (const float*)d_in[15];
    const float* Ve  = (const float*)d_in[16];
    const float* Vd  = (const float*)d_in[17];
    const float* gf  = (const float*)d_in[18];
    const float* bf  = (const float*)d_in[19];
    float* out = (float*)d_out;

    // ---------------- workspace layout ----------------
    float* ws  = (float*)d_ws;
    float* pos = ws;                        // 262144 f
    float* C   = pos + 262144;              // 4M f
    float* X2  = C   + 4194304;
    float* OUT = X2  + 4194304;
    float* PF  = OUT + 4194304;
    u16* ub = (u16*)(PF + 4194304);
    u16* Cb  = ub;  ub += 4194304;          // bf16 carry [8192][512]
    u16* X2b = ub;  ub += 4194304;          // bf16 x2    [8192][512]
    u16* Qbf = ub;  ub += 4194304;          // [H][8192][64]
    u16* Kbf = ub;  ub += 4194304;
    u16* Vtb = ub;  ub += 4194304;          // [H*16][64][512]
    u16* Abf = ub;  ub += 4194304;          // attn out bf16 [8192][512]
    u16* Hb  = Qbf;                         // FF hidden [8192][2048] aliases Q|K|Vt|A (exactly 16.78M u16)
    u16* WQb = ub; ub += 1572864;           // 6 x [512][512]
    u16* WKb = ub; ub += 1572864;
    u16* WVb = ub; ub += 1572864;
    u16* WOt = ub; ub += 1572864;           // 6 x [512][512] (transposed)
    u16* W1t = ub; ub += 6291456;           // 6 x [2048][512] (transposed)
    u16* W2t = ub; ub += 6291456;           // 6 x [512][2048] (transposed)
    float* x9 = (float*)ub;                 // 8192 f
    float* zb = x9 + 8192;                  // 160000 f

    pos_kernel<<<1024, 256, 0, stream>>>(pos);
    embed_kernel<<<4096, 256, 0, stream>>>(xi, emb, pos, C, Cb);

    // weight conversion (once per call)
    cvt_b16_kernel<<<1536, 256, 0, stream>>>(WQ, WQb, 393216);
    cvt_b16_kernel<<<1536, 256, 0, stream>>>(WK, WKb, 393216);
    cvt_b16_kernel<<<1536, 256, 0, stream>>>(WV, WVb, 393216);
    tcvt_b16_kernel<<<dim3(8,  8, 6), 256, 0, stream>>>(WO, WOt, 512, 512);
    tcvt_b16_kernel<<<dim3(8, 32, 6), 256, 0, stream>>>(W1, W1t, 512, 2048);
    tcvt_b16_kernel<<<dim3(32, 8, 6), 256, 0, stream>>>(W2, W2t, 2048, 512);

    const float scale = 1.0f / sqrtf(512.0f);
    const dim3 g4(64, 4), g16(64, 16);

    for (int l = 0; l < NLAYER; ++l) {
        const u16* wq = WQb + (size_t)l * 262144;
        const u16* wk = WKb + (size_t)l * 262144;
        const u16* wv = WVb + (size_t)l * 262144;
        const u16* wo = WOt + (size_t)l * 262144;
        const u16* w1 = W1t + (size_t)l * 1048576;
        const u16* w2 = W2t + (size_t)l * 1048576;

        gemm_bf16<EG_QK>       <<<g4,  256, 0, stream>>>(Cb,  wq, nullptr, Qbf, 512,  512);
        gemm_bf16<EG_QK>       <<<g4,  256, 0, stream>>>(Cb,  wk, nullptr, Kbf, 512,  512);
        gemm_bf16<EG_VT>       <<<g4,  256, 0, stream>>>(Cb,  wv, nullptr, Vtb, 512,  512);
        attn_mfma              <<<4096,256, 0, stream>>>(Qbf, Kbf, Vtb, ga + l*8, ba + l*8, Abf, scale);
        gemm_bf16<EG_F32>      <<<g4,  256, 0, stream>>>(Abf, wo, nullptr, PF, 512, 512);
        ln_res_kernel          <<<2048,256, 0, stream>>>(PF, C, g1, be1, l, X2, X2b, nullptr, nullptr);
        gemm_bf16<EG_BRELU_B16><<<g16, 256, 0, stream>>>(X2b, w1, b1 + l*2048, Hb, 2048, 512);
        gemm_bf16<EG_BIAS_F32> <<<g4,  256, 0, stream>>>(Hb,  w2, b2 + l*512,  PF, 512, 2048);
        ln_res_kernel          <<<2048,256, 0, stream>>>(PF, X2, g2, be2, l, OUT, nullptr, C, Cb);
    }

    fin_ve_kernel<<<2048, 256, 0, stream>>>(OUT, Ve, x9);
    fin_vd_kernel<<<157,  256, 0, stream>>>(x9, Vd, zb);
    fin_sm_kernel<<<16,   256, 0, stream>>>(zb, gf, bf, out);
}

// Round 4
// 1307.855 us; speedup vs baseline: 7.1561x; 1.1447x over previous
//
#include <hip/hip_runtime.h>
#include <hip/hip_bf16.h>
#include <math.h>

#define N_TOK 8192
#define DMODEL 512
#define NHEAD 8
#define HDIM 64
#define SEQ 512
#define BATCH 16
#define FFDIM 2048
#define NLAYER 6
#define NCLS 10000

typedef unsigned short u16;
typedef __attribute__((ext_vector_type(8))) short bf16x8;
typedef __attribute__((ext_vector_type(8))) unsigned short u16x8;
typedef __attribute__((ext_vector_type(4))) unsigned short u16x4;
typedef __attribute__((ext_vector_type(4))) float f32x4;

__device__ __forceinline__ u16 f2b(float x) {   // RNE f32 -> bf16 (finite inputs)
    unsigned int u = __float_as_uint(x);
    u += 0x7fffu + ((u >> 16) & 1u);
    return (u16)(u >> 16);
}

__device__ __forceinline__ void gl_lds16(const void* g, void* l) {
    __builtin_amdgcn_global_load_lds(
        (const __attribute__((address_space(1))) unsigned int*)g,
        (__attribute__((address_space(3))) unsigned int*)l, 16, 0, 0);
}

// ---------------- positional table: fp64 rotation recurrence ------------------
// block bb covers s in [bb*32, bb*32+32); thread i = column. angle = s * base_i.
__global__ __launch_bounds__(512) void pos_kernel(float* __restrict__ pos) {
    const int i = threadIdx.x;
    const int s0 = blockIdx.x * 32;
    const double bse = pow(10000.0, -(double)(i & ~1) / 512.0);
    const double cb = cos(bse), sb = sin(bse);
    const double a0 = (double)s0 * bse;
    double sn = sin(a0), cs = cos(a0);
    const bool odd = i & 1;
    for (int k = 0; k < 32; ++k) {
        pos[(size_t)(s0 + k) * 512 + i] = (float)(odd ? cs : sn);
        const double ns = sn * cb + cs * sb;
        cs = cs * cb - sn * sb;
        sn = ns;
    }
}

// ---------------- embedding: C = 2*emb[x] + pos (f32 + bf16 copies) ----------
__global__ __launch_bounds__(256) void embed_kernel(const int* __restrict__ xi,
        const float* __restrict__ emb, const float* __restrict__ pos,
        float* __restrict__ C, u16* __restrict__ Cb) {
    const int idx = blockIdx.x * 256 + threadIdx.x;   // over N_TOK*128 float4s
    const int n = idx >> 7, d4 = (idx & 127) << 2;
    const int row = xi[n];
    const int s = n & 511;
    const float4 e = *(const float4*)&emb[(size_t)row * 512 + d4];
    const float4 p = *(const float4*)&pos[(size_t)s * 512 + d4];
    float4 o;
    o.x = 2.f * e.x + p.x; o.y = 2.f * e.y + p.y;
    o.z = 2.f * e.z + p.z; o.w = 2.f * e.w + p.w;
    *(float4*)&C[(size_t)n * 512 + d4] = o;
    u16x4 ob = { f2b(o.x), f2b(o.y), f2b(o.z), f2b(o.w) };
    *(u16x4*)&Cb[(size_t)n * 512 + d4] = ob;
}

// ---------------- weight converts --------------------------------------------
// WQ|WK|WV (each [L][512][512], already [N][K]) -> WQKVb [L][3*512][512] bf16
__global__ __launch_bounds__(256) void cvt3_kernel(const float* __restrict__ q,
        const float* __restrict__ k, const float* __restrict__ v,
        u16* __restrict__ dst) {
    const int i = blockIdx.x * 256 + threadIdx.x;      // 1179648 float4s total
    const int l = i / 196608;
    const int rem = i - l * 196608;
    const int m = rem >> 16, r = rem & 65535;
    const float* src = (m == 0 ? q : (m == 1 ? k : v));
    const float4 vv = ((const float4*)src)[(size_t)l * 65536 + r];
    u16x4 o = { f2b(vv.x), f2b(vv.y), f2b(vv.z), f2b(vv.w) };
    *(u16x4*)&dst[(size_t)l * 786432 + (size_t)m * 262144 + (size_t)r * 4] = o;
}

// src [Kd][Nd] f32 per layer (z) -> dst [Nd][Kd] bf16
__global__ __launch_bounds__(256) void tcvt_b16_kernel(const float* __restrict__ src,
        u16* __restrict__ dst, int Kd, int Nd) {
    __shared__ u16 t[64][65];
    const int k0 = blockIdx.x * 64, n0 = blockIdx.y * 64;
    const size_t off = (size_t)blockIdx.z * Kd * Nd;
    src += off; dst += off;
    const int cx = threadIdx.x & 63, r0 = threadIdx.x >> 6;
    #pragma unroll
    for (int i = 0; i < 16; ++i) {
        const int r = r0 * 16 + i;
        t[cx][r] = f2b(src[(size_t)(k0 + r) * Nd + n0 + cx]);
    }
    __syncthreads();
    #pragma unroll
    for (int i = 0; i < 16; ++i) {
        const int nn = r0 * 16 + i;
        dst[(size_t)(n0 + nn) * Kd + k0 + cx] = t[nn][cx];
    }
}

// ---------------- bf16 MFMA GEMM: C = A[8192,K] * Bt[N,K]^T -------------------
// BM x 128 tile, BK=64, 4 waves (2x2). global_load_lds w/ source pre-swizzle;
// frag ds_read_b128 XOR-swizzled (T2).
enum { EG_QKV3 = 0, EG_F32 = 1, EG_BIAS_F32 = 2, EG_BRELU_B16 = 3 };

template<int BM, int EPI>
__global__ __launch_bounds__(256)
void gemm_bf16(const u16* __restrict__ A, const u16* __restrict__ Bt,
               const float* __restrict__ bias, void* __restrict__ Cout,
               int N, int K) {
    constexpr int MF = BM / 32;              // m-frags per wave
    __shared__ u16 As[BM * 64];
    __shared__ u16 Bs[128 * 64];
    const int tid = threadIdx.x, w = tid >> 6, l = tid & 63;
    const int g = l >> 4, c = l & 15;
    const int wm = w >> 1, wn = w & 1;
    const int bm = blockIdx.x * BM, bn = blockIdx.y * 128;
    const int sr = l >> 3, sc8 = l & 7;

    const f32x4 zero = {0.f, 0.f, 0.f, 0.f};
    f32x4 acc[MF][4];
    #pragma unroll
    for (int i = 0; i < MF; ++i)
        #pragma unroll
        for (int j = 0; j < 4; ++j) acc[i][j] = zero;

    for (int k0 = 0; k0 < K; k0 += 64) {
        __syncthreads();
        #pragma unroll
        for (int i = 0; i < MF; ++i) {
            const int rb = w * (BM / 4) + i * 8;
            const int r = rb + sr;
            const int ck = (sc8 ^ (r & 7)) * 8;   // source pre-swizzle (involution)
            gl_lds16(A + (size_t)(bm + r) * K + k0 + ck, &As[rb * 64]);
        }
        #pragma unroll
        for (int i = 0; i < 4; ++i) {
            const int rb = w * 32 + i * 8;
            const int r = rb + sr;
            const int ck = (sc8 ^ (r & 7)) * 8;
            gl_lds16(Bt + (size_t)(bn + r) * K + k0 + ck, &Bs[rb * 64]);
        }
        __syncthreads();
        #pragma unroll
        for (int ks = 0; ks < 2; ++ks) {
            bf16x8 af[MF], bfv[4];
            #pragma unroll
            for (int q = 0; q < MF; ++q) {
                const int ra = wm * (BM / 2) + q * 16 + c;
                af[q] = *(const bf16x8*)((const char*)As +
                        ((ra * 128 + ks * 64 + g * 16) ^ ((ra & 7) << 4)));
            }
            #pragma unroll
            for (int q = 0; q < 4; ++q) {
                const int rb2 = wn * 64 + q * 16 + c;
                bfv[q] = *(const bf16x8*)((const char*)Bs +
                        ((rb2 * 128 + ks * 64 + g * 16) ^ ((rb2 & 7) << 4)));
            }
            #pragma unroll
            for (int mf = 0; mf < MF; ++mf)
                #pragma unroll
                for (int nf = 0; nf < 4; ++nf)
                    acc[mf][nf] = __builtin_amdgcn_mfma_f32_16x16x32_bf16(
                        af[mf], bfv[nf], acc[mf][nf], 0, 0, 0);
        }
    }

    #pragma unroll
    for (int mf = 0; mf < MF; ++mf) {
        #pragma unroll
        for (int nf = 0; nf < 4; ++nf) {
            const int n  = bn + wn * 64 + nf * 16 + c;
            const int m0 = bm + wm * (BM / 2) + mf * 16 + g * 4;
            if (EPI == EG_QKV3) {
                // seg 0/1 -> Q/K head-major [H][8192][64]; seg 2 -> V^T [H*16][64][512]
                u16* o = (u16*)Cout;
                const int seg = n >> 9, nn = n & 511;
                if (seg < 2) {
                    u16* dst = o + (size_t)seg * 4194304;
                    const size_t b0 = (size_t)(nn & 7) * N_TOK * 64 + (nn >> 3);
                    #pragma unroll
                    for (int r = 0; r < 4; ++r)
                        dst[b0 + (size_t)(m0 + r) * 64] = f2b(acc[mf][nf][r]);
                } else {
                    u16* dst = o + (size_t)2 * 4194304;
                    const int h = nn & 7, d = nn >> 3, bb = m0 >> 9, s0 = m0 & 511;
                    u16x4 pk = { f2b(acc[mf][nf][0]), f2b(acc[mf][nf][1]),
                                 f2b(acc[mf][nf][2]), f2b(acc[mf][nf][3]) };
                    *(u16x4*)&dst[((size_t)(h * 16 + bb) * 64 + d) * 512 + s0] = pk;
                }
            } else if (EPI == EG_F32) {
                float* o = (float*)Cout;
                #pragma unroll
                for (int r = 0; r < 4; ++r)
                    o[(size_t)(m0 + r) * N + n] = acc[mf][nf][r];
            } else if (EPI == EG_BIAS_F32) {
                float* o = (float*)Cout;
                const float bv = bias[n];
                #pragma unroll
                for (int r = 0; r < 4; ++r)
                    o[(size_t)(m0 + r) * N + n] = acc[mf][nf][r] + bv;
            } else {  // EG_BRELU_B16
                u16* o = (u16*)Cout;
                const float bv = bias[n];
                #pragma unroll
                for (int r = 0; r < 4; ++r)
                    o[(size_t)(m0 + r) * N + n] = f2b(fmaxf(acc[mf][nf][r] + bv, 0.f));
            }
        }
    }
}

// ---------------- fused bf16-MFMA attention (2-barrier, folded LN+exp) -------
// hb-major block order: all 32 q-chunks of one (h,b) share an XCD (L2-local K/V).
__global__ __launch_bounds__(256)
void attn_mfma(const u16* __restrict__ Qb, const u16* __restrict__ Kb,
               const u16* __restrict__ Vt, const float* __restrict__ ga,
               const float* __restrict__ ba, u16* __restrict__ A, float scale) {
    __shared__ __align__(16) u16 al[16 * 536];
    __shared__ float stS[64], stQ[64], stE[64];
    const int bid = blockIdx.x;
    const int hb = bid & 127, qc = bid >> 7;
    const int h = hb >> 4, b = hb & 15;
    const int tid = threadIdx.x, w = tid >> 6, l = tid & 63;
    const int g = l >> 4, c = l & 15;
    const float gah = ga[h], bah = ba[h];
    const size_t qkbase = ((size_t)h * N_TOK + (size_t)b * SEQ) * 64;
    const size_t vtbase = ((size_t)(h * 16 + b)) * 64 * 512;

    const u16* qrow = Qb + qkbase + (size_t)(qc * 16 + c) * 64;
    const bf16x8 qf0 = *(const bf16x8*)(qrow + g * 8);
    const bf16x8 qf1 = *(const bf16x8*)(qrow + 32 + g * 8);

    // ---- scores: S[16][128] per wave, raw (unscaled) ------------------------
    f32x4 acc[8];
    __builtin_amdgcn_s_setprio(1);
    #pragma unroll
    for (int tt = 0; tt < 8; ++tt) {
        const u16* krow = Kb + qkbase + (size_t)(w * 128 + tt * 16 + c) * 64;
        const bf16x8 kf0 = *(const bf16x8*)(krow + g * 8);
        const bf16x8 kf1 = *(const bf16x8*)(krow + 32 + g * 8);
        f32x4 z = {0.f, 0.f, 0.f, 0.f};
        z = __builtin_amdgcn_mfma_f32_16x16x32_bf16(qf0, kf0, z, 0, 0, 0);
        z = __builtin_amdgcn_mfma_f32_16x16x32_bf16(qf1, kf1, z, 0, 0, 0);
        acc[tt] = z;
    }
    __builtin_amdgcn_s_setprio(0);

    // ---- raw row stats -------------------------------------------------------
    float sm[4] = {0.f,0.f,0.f,0.f}, sq[4] = {0.f,0.f,0.f,0.f};
    #pragma unroll
    for (int tt = 0; tt < 8; ++tt)
        #pragma unroll
        for (int r = 0; r < 4; ++r) {
            const float v = acc[tt][r];
            sm[r] += v; sq[r] = fmaf(v, v, sq[r]);
        }
    #pragma unroll
    for (int off = 1; off < 16; off <<= 1)
        #pragma unroll
        for (int r = 0; r < 4; ++r) {
            sm[r] += __shfl_xor(sm[r], off);
            sq[r] += __shfl_xor(sq[r], off);
        }
    if (c == 0) {
        #pragma unroll
        for (int r = 0; r < 4; ++r) { stS[w*16 + g*4 + r] = sm[r]; stQ[w*16 + g*4 + r] = sq[r]; }
    }
    __syncthreads();

    // ---- fold scale+LN+log2e into p = exp2(acc*A2 + B2); no max-sub ----------
    // (z-score bounded by (n-1)/sqrt(n)~22.6 -> exp <= 7e9, f32/bf16-safe)
    const float LOG2E = 1.4426950408889634f;
    float A2[4], B2[4], sme[4] = {0.f,0.f,0.f,0.f};
    #pragma unroll
    for (int r = 0; r < 4; ++r) {
        const int rw = g*4 + r;
        const float S  = (stS[rw] + stS[16+rw] + stS[32+rw] + stS[48+rw]) * scale;
        const float Qq = (stQ[rw] + stQ[16+rw] + stQ[32+rw] + stQ[48+rw]) * scale * scale;
        const float mu = S * (1.f/512.f);
        const float var = (Qq - 512.f * mu * mu) * (1.f/511.f);
        const float rg = rsqrtf(var + 1e-8f) * gah;
        A2[r] = scale * rg * LOG2E;
        B2[r] = (bah - mu * rg) * LOG2E;
    }
    #pragma unroll
    for (int tt = 0; tt < 8; ++tt)
        #pragma unroll
        for (int r = 0; r < 4; ++r) {
            const float p = exp2f(fmaf(acc[tt][r], A2[r], B2[r]));
            acc[tt][r] = p; sme[r] += p;
        }
    #pragma unroll
    for (int off = 1; off < 16; off <<= 1)
        #pragma unroll
        for (int r = 0; r < 4; ++r) sme[r] += __shfl_xor(sme[r], off);
    if (c == 0) {
        #pragma unroll
        for (int r = 0; r < 4; ++r) stE[w*16 + g*4 + r] = sme[r];
    }
    #pragma unroll
    for (int r = 0; r < 4; ++r)
        #pragma unroll
        for (int tt = 0; tt < 8; ++tt)
            al[(size_t)(g*4 + r) * 536 + w*128 + tt*16 + c] = f2b(acc[tt][r]);
    __syncthreads();

    // ---- PV on unnormalized p; normalize output by inv -----------------------
    f32x4 o = {0.f, 0.f, 0.f, 0.f};
    __builtin_amdgcn_s_setprio(1);
    #pragma unroll
    for (int ks = 0; ks < 16; ++ks) {
        const bf16x8 af = *(const bf16x8*)&al[(size_t)c * 536 + ks*32 + g*8];
        const bf16x8 vf = *(const bf16x8*)(Vt + vtbase + (size_t)(w*16 + c) * 512 + ks*32 + g*8);
        o = __builtin_amdgcn_mfma_f32_16x16x32_bf16(af, vf, o, 0, 0, 0);
    }
    __builtin_amdgcn_s_setprio(0);
    #pragma unroll
    for (int r = 0; r < 4; ++r) {
        const int rw = g*4 + r;
        const float inv = 1.f / (stE[rw] + stE[16+rw] + stE[32+rw] + stE[48+rw]);
        A[((size_t)(b * 512 + qc * 16 + rw)) * 512 + h * 64 + w*16 + c] = f2b(o[r] * inv);
    }
}

// ---------------- LayerNorm(X + R); optional bf16 copy, carry accumulate -----
__global__ __launch_bounds__(256)
void ln_res_kernel(const float* __restrict__ X, const float* __restrict__ R,
                   const float* __restrict__ gp, const float* __restrict__ bp,
                   int lidx, float* __restrict__ Y, u16* __restrict__ Yb,
                   float* __restrict__ Cacc, u16* __restrict__ Cb) {
    const int tid = threadIdx.x, w = tid >> 6, l = tid & 63;
    const size_t row = (size_t)blockIdx.x * 4 + w;
    const float g = gp[lidx], bb = bp[lidx];
    const float* x = X + row * 512;
    const float* r = R + row * 512;
    float v[8];
    const float4 a0 = *(const float4*)&x[l * 8], a1 = *(const float4*)&x[l * 8 + 4];
    const float4 r0 = *(const float4*)&r[l * 8], r1 = *(const float4*)&r[l * 8 + 4];
    v[0] = a0.x + r0.x; v[1] = a0.y + r0.y; v[2] = a0.z + r0.z; v[3] = a0.w + r0.w;
    v[4] = a1.x + r1.x; v[5] = a1.y + r1.y; v[6] = a1.z + r1.z; v[7] = a1.w + r1.w;
    float s = 0.f, sq = 0.f;
    #pragma unroll
    for (int i = 0; i < 8; ++i) { s += v[i]; sq = fmaf(v[i], v[i], sq); }
    #pragma unroll
    for (int o = 1; o < 64; o <<= 1) { s += __shfl_xor(s, o); sq += __shfl_xor(sq, o); }
    const float mu   = s * (1.f / 512.f);
    const float var  = (sq - 512.f * mu * mu) * (1.f / 511.f);
    const float rstd = rsqrtf(var + 1e-8f);
    float y[8];
    #pragma unroll
    for (int i = 0; i < 8; ++i) y[i] = fmaf((v[i] - mu) * rstd, g, bb);
    *(float4*)&Y[row * 512 + l * 8]     = *(float4*)&y[0];
    *(float4*)&Y[row * 512 + l * 8 + 4] = *(float4*)&y[4];
    if (Yb) {
        u16x8 yb;
        #pragma unroll
        for (int i = 0; i < 8; ++i) yb[i] = f2b(y[i]);
        *(u16x8*)&Yb[row * 512 + l * 8] = yb;
    }
    if (Cacc) {
        float cv[8];
        float4 c0 = *(float4*)&Cacc[row * 512 + l * 8];
        float4 c1 = *(float4*)&Cacc[row * 512 + l * 8 + 4];
        cv[0] = c0.x + y[0]; cv[1] = c0.y + y[1]; cv[2] = c0.z + y[2]; cv[3] = c0.w + y[3];
        cv[4] = c1.x + y[4]; cv[5] = c1.y + y[5]; cv[6] = c1.z + y[6]; cv[7] = c1.w + y[7];
        *(float4*)&Cacc[row * 512 + l * 8]     = *(float4*)&cv[0];
        *(float4*)&Cacc[row * 512 + l * 8 + 4] = *(float4*)&cv[4];
        u16x8 cb;
        #pragma unroll
        for (int i = 0; i < 8; ++i) cb[i] = f2b(cv[i]);
        *(u16x8*)&Cb[row * 512 + l * 8] = cb;
    }
}

// ---------------- final head: x9 = X8 @ V_e ----------------------------------
__global__ __launch_bounds__(256)
void fin_ve_kernel(const float* __restrict__ X8, const float* __restrict__ Ve,
                   float* __restrict__ x9) {
    const int tid = threadIdx.x, w = tid >> 6, l = tid & 63;
    const size_t row = (size_t)blockIdx.x * 4 + w;
    const float* x = X8 + row * 512;
    float s = 0.f;
    #pragma unroll
    for (int i = 0; i < 8; ++i) s = fmaf(x[l * 8 + i], Ve[l * 8 + i], s);
    #pragma unroll
    for (int o = 1; o < 64; o <<= 1) s += __shfl_xor(s, o);
    if (l == 0) x9[row] = s;
}

// ---------------- z[b,c] = sum_s x9[b,s] * Vd[s,c] ---------------------------
__global__ __launch_bounds__(256)
void fin_vd_kernel(const float* __restrict__ x9, const float* __restrict__ Vd,
                   float* __restrict__ z) {
    __shared__ float red[4][16][65];
    const int tid = threadIdx.x, l = tid & 63, sch = tid >> 6;
    const int c = blockIdx.x * 64 + l;
    float acc[16];
    #pragma unroll
    for (int b = 0; b < 16; ++b) acc[b] = 0.f;
    if (c < NCLS) {
        for (int s = sch * 128; s < sch * 128 + 128; ++s) {
            const float vd = Vd[(size_t)s * NCLS + c];
            #pragma unroll
            for (int b = 0; b < 16; ++b) acc[b] = fmaf(x9[b * 512 + s], vd, acc[b]);
        }
    }
    #pragma unroll
    for (int b = 0; b < 16; ++b) red[sch][b][l] = acc[b];
    __syncthreads();
    if (sch == 0 && c < NCLS) {
        #pragma unroll
        for (int b = 0; b < 16; ++b)
            z[(size_t)b * NCLS + c] = red[0][b][l] + red[1][b][l] + red[2][b][l] + red[3][b][l];
    }
}

// ---------------- final norm (ddof=1 over 10000) + softmax -------------------
__global__ __launch_bounds__(256)
void fin_sm_kernel(const float* __restrict__ z, const float* __restrict__ gp,
                   const float* __restrict__ bp, float* __restrict__ out) {
    __shared__ float zs[NCLS];
    __shared__ float red[4];
    __shared__ float red2[4];
    const int b = blockIdx.x, tid = threadIdx.x, w = tid >> 6, l = tid & 63;
    float s = 0.f, sq = 0.f;
    for (int i = tid; i < NCLS; i += 256) {
        const float v = z[(size_t)b * NCLS + i];
        zs[i] = v; s += v; sq = fmaf(v, v, sq);
    }
    #pragma unroll
    for (int o = 1; o < 64; o <<= 1) { s += __shfl_xor(s, o); sq += __shfl_xor(sq, o); }
    if (l == 0) { red[w] = s; red2[w] = sq; }
    __syncthreads();
    s  = red[0] + red[1] + red[2] + red[3];
    sq = red2[0] + red2[1] + red2[2] + red2[3];
    const float mu   = s / 10000.f;
    const float var  = (sq - 10000.f * mu * mu) / 9999.f;
    const float rstd = rsqrtf(var + 1e-8f);
    const float g = gp[0], be = bp[0];
    __syncthreads();
    float mx = -1e30f;
    for (int i = tid; i < NCLS; i += 256) {
        const float e = fmaf((zs[i] - mu) * rstd, g, be);
        zs[i] = e; mx = fmaxf(mx, e);
    }
    #pragma unroll
    for (int o = 1; o < 64; o <<= 1) mx = fmaxf(mx, __shfl_xor(mx, o));
    if (l == 0) red[w] = mx;
    __syncthreads();
    mx = fmaxf(fmaxf(red[0], red[1]), fmaxf(red[2], red[3]));
    float es = 0.f;
    for (int i = tid; i < NCLS; i += 256) {
        const float p = expf(zs[i] - mx);
        zs[i] = p; es += p;
    }
    #pragma unroll
    for (int o = 1; o < 64; o <<= 1) es += __shfl_xor(es, o);
    if (l == 0) red2[w] = es;
    __syncthreads();
    es = red2[0] + red2[1] + red2[2] + red2[3];
    const float inv = 1.f / es;
    for (int i = tid; i < NCLS; i += 256) out[(size_t)b * NCLS + i] = zs[i] * inv;
}

// =============================================================================
extern "C" void kernel_launch(void* const* d_in, const int* in_sizes, int n_in,
                              void* d_out, int out_size, void* d_ws, size_t ws_size,
                              hipStream_t stream) {
    (void)in_sizes; (void)n_in; (void)out_size; (void)ws_size;
    const int*   xi  = (const int*)d_in[0];
    const float* emb = (const float*)d_in[1];
    const float* WQ  = (const float*)d_in[2];
    const float* WK  = (const float*)d_in[3];
    const float* WV  = (const float*)d_in[4];
    const float* WO  = (const float*)d_in[5];
    const float* W1  = (const float*)d_in[6];
    const float* b1  = (const float*)d_in[7];
    const float* W2  = (const float*)d_in[8];
    const float* b2  = (const float*)d_in[9];
    const float* ga  = (const float*)d_in[10];
    const float* ba  = (const float*)d_in[11];
    const float* g1  = (const float*)d_in[12];
    const float* be1 = (const float*)d_in[13];
    const float* g2  = (const float*)d_in[14];
    const float* be2 = (const float*)d_in[15];
    const float* Ve  = (const float*)d_in[16];
    const float* Vd  = (const float*)d_in[17];
    const float* gf  = (const float*)d_in[18];
    const float* bf  = (const float*)d_in[19];
    float* out = (float*)d_out;

    // ---------------- workspace layout ----------------
    float* ws  = (float*)d_ws;
    float* pos = ws;                        // 262144 f
    float* C   = pos + 262144;              // 4M f
    float* X2  = C   + 4194304;
    float* OUT = X2  + 4194304;
    float* PF  = OUT + 4194304;
    u16* ub = (u16*)(PF + 4194304);
    u16* Cb  = ub;  ub += 4194304;          // bf16 carry [8192][512]
    u16* X2b = ub;  ub += 4194304;          // bf16 x2    [8192][512]
    u16* Qbf = ub;  ub += 4194304;          // [H][8192][64]; K at +4M, Vt at +8M
    u16* Kbf = ub;  ub += 4194304;
    u16* Vtb = ub;  ub += 4194304;          // [H*16][64][512]
    u16* Abf = ub;  ub += 4194304;          // attn out bf16 [8192][512]
    u16* Hb  = Qbf;                         // FF hidden [8192][2048] aliases Q|K|Vt|A
    u16* WQKVb = ub; ub += 4718592;         // 6 x [1536][512]
    u16* WOt = ub; ub += 1572864;           // 6 x [512][512] (transposed)
    u16* W1t = ub; ub += 6291456;           // 6 x [2048][512] (transposed)
    u16* W2t = ub; ub += 6291456;           // 6 x [512][2048] (transposed)
    float* x9 = (float*)ub;                 // 8192 f
    float* zb = x9 + 8192;                  // 160000 f

    pos_kernel<<<16, 512, 0, stream>>>(pos);
    embed_kernel<<<4096, 256, 0, stream>>>(xi, emb, pos, C, Cb);

    // weight conversion (once per call)
    cvt3_kernel<<<4608, 256, 0, stream>>>(WQ, WK, WV, WQKVb);
    tcvt_b16_kernel<<<dim3(8,  8, 6), 256, 0, stream>>>(WO, WOt, 512, 512);
    tcvt_b16_kernel<<<dim3(8, 32, 6), 256, 0, stream>>>(W1, W1t, 512, 2048);
    tcvt_b16_kernel<<<dim3(32, 8, 6), 256, 0, stream>>>(W2, W2t, 2048, 512);

    const float scale = 1.0f / sqrtf(512.0f);

    for (int l = 0; l < NLAYER; ++l) {
        const u16* wqkv = WQKVb + (size_t)l * 786432;
        const u16* wo = WOt + (size_t)l * 262144;
        const u16* w1 = W1t + (size_t)l * 1048576;
        const u16* w2 = W2t + (size_t)l * 1048576;

        gemm_bf16<128, EG_QKV3>     <<<dim3(64, 12), 256, 0, stream>>>(Cb, wqkv, nullptr, Qbf, 1536, 512);
        attn_mfma                   <<<4096, 256, 0, stream>>>(Qbf, Kbf, Vtb, ga + l*8, ba + l*8, Abf, scale);
        gemm_bf16<64, EG_F32>       <<<dim3(128, 4), 256, 0, stream>>>(Abf, wo, nullptr, PF, 512, 512);
        ln_res_kernel               <<<2048, 256, 0, stream>>>(PF, C, g1, be1, l, X2, X2b, nullptr, nullptr);
        gemm_bf16<128, EG_BRELU_B16><<<dim3(64, 16), 256, 0, stream>>>(X2b, w1, b1 + l*2048, Hb, 2048, 512);
        gemm_bf16<64, EG_BIAS_F32>  <<<dim3(128, 4), 256, 0, stream>>>(Hb, w2, b2 + l*512, PF, 512, 2048);
        ln_res_kernel               <<<2048, 256, 0, stream>>>(PF, X2, g2, be2, l, OUT, nullptr, C, Cb);
    }

    fin_ve_kernel<<<2048, 256, 0, stream>>>(OUT, Ve, x9);
    fin_vd_kernel<<<157,  256, 0, stream>>>(x9, Vd, zb);
    fin_sm_kernel<<<16,   256, 0, stream>>>(zb, gf, bf, out);
}

// Round 5
// 1235.276 us; speedup vs baseline: 7.5766x; 1.0588x over previous
//
#include <hip/hip_runtime.h>
#include <hip/hip_bf16.h>
#include <math.h>

#define N_TOK 8192
#define DMODEL 512
#define NHEAD 8
#define HDIM 64
#define SEQ 512
#define BATCH 16
#define FFDIM 2048
#define NLAYER 6
#define NCLS 10000

typedef unsigned short u16;
typedef __attribute__((ext_vector_type(8))) short bf16x8;
typedef __attribute__((ext_vector_type(8))) unsigned short u16x8;
typedef __attribute__((ext_vector_type(4))) unsigned short u16x4;
typedef __attribute__((ext_vector_type(4))) float f32x4;

__device__ __forceinline__ u16 f2b(float x) {   // RNE f32 -> bf16 (finite inputs)
    unsigned int u = __float_as_uint(x);
    u += 0x7fffu + ((u >> 16) & 1u);
    return (u16)(u >> 16);
}

__device__ __forceinline__ void gl_lds16(const void* g, void* l) {
    __builtin_amdgcn_global_load_lds(
        (const __attribute__((address_space(1))) unsigned int*)g,
        (__attribute__((address_space(3))) unsigned int*)l, 16, 0, 0);
}

// ---------------- positional table: fp64 rotation recurrence ------------------
__global__ __launch_bounds__(512) void pos_kernel(float* __restrict__ pos) {
    const int i = threadIdx.x;
    const int s0 = blockIdx.x * 32;
    const double bse = pow(10000.0, -(double)(i & ~1) / 512.0);
    const double cb = cos(bse), sb = sin(bse);
    const double a0 = (double)s0 * bse;
    double sn = sin(a0), cs = cos(a0);
    const bool odd = i & 1;
    for (int k = 0; k < 32; ++k) {
        pos[(size_t)(s0 + k) * 512 + i] = (float)(odd ? cs : sn);
        const double ns = sn * cb + cs * sb;
        cs = cs * cb - sn * sb;
        sn = ns;
    }
}

// ---------------- embedding: C = 2*emb[x] + pos (f32 + bf16 copies) ----------
__global__ __launch_bounds__(256) void embed_kernel(const int* __restrict__ xi,
        const float* __restrict__ emb, const float* __restrict__ pos,
        float* __restrict__ C, u16* __restrict__ Cb) {
    const int idx = blockIdx.x * 256 + threadIdx.x;   // over N_TOK*128 float4s
    const int n = idx >> 7, d4 = (idx & 127) << 2;
    const int row = xi[n];
    const int s = n & 511;
    const float4 e = *(const float4*)&emb[(size_t)row * 512 + d4];
    const float4 p = *(const float4*)&pos[(size_t)s * 512 + d4];
    float4 o;
    o.x = 2.f * e.x + p.x; o.y = 2.f * e.y + p.y;
    o.z = 2.f * e.z + p.z; o.w = 2.f * e.w + p.w;
    *(float4*)&C[(size_t)n * 512 + d4] = o;
    u16x4 ob = { f2b(o.x), f2b(o.y), f2b(o.z), f2b(o.w) };
    *(u16x4*)&Cb[(size_t)n * 512 + d4] = ob;
}

// ---------------- weight converts --------------------------------------------
__global__ __launch_bounds__(256) void cvt3_kernel(const float* __restrict__ q,
        const float* __restrict__ k, const float* __restrict__ v,
        u16* __restrict__ dst) {
    const int i = blockIdx.x * 256 + threadIdx.x;      // 1179648 float4s total
    const int l = i / 196608;
    const int rem = i - l * 196608;
    const int m = rem >> 16, r = rem & 65535;
    const float* src = (m == 0 ? q : (m == 1 ? k : v));
    const float4 vv = ((const float4*)src)[(size_t)l * 65536 + r];
    u16x4 o = { f2b(vv.x), f2b(vv.y), f2b(vv.z), f2b(vv.w) };
    *(u16x4*)&dst[(size_t)l * 786432 + (size_t)m * 262144 + (size_t)r * 4] = o;
}

// src [Kd][Nd] f32 per layer (z) -> dst [Nd][Kd] bf16
__global__ __launch_bounds__(256) void tcvt_b16_kernel(const float* __restrict__ src,
        u16* __restrict__ dst, int Kd, int Nd) {
    __shared__ u16 t[64][65];
    const int k0 = blockIdx.x * 64, n0 = blockIdx.y * 64;
    const size_t off = (size_t)blockIdx.z * Kd * Nd;
    src += off; dst += off;
    const int cx = threadIdx.x & 63, r0 = threadIdx.x >> 6;
    #pragma unroll
    for (int i = 0; i < 16; ++i) {
        const int r = r0 * 16 + i;
        t[cx][r] = f2b(src[(size_t)(k0 + r) * Nd + n0 + cx]);
    }
    __syncthreads();
    #pragma unroll
    for (int i = 0; i < 16; ++i) {
        const int nn = r0 * 16 + i;
        dst[(size_t)(n0 + nn) * Kd + k0 + cx] = t[nn][cx];
    }
}

// ---------------- bf16 MFMA GEMM: C = A[8192,K] * Bt[N,K]^T -------------------
enum { EG_QKV3 = 0, EG_F32 = 1, EG_BIAS_F32 = 2, EG_BRELU_B16 = 3 };

template<int BM, int EPI>
__global__ __launch_bounds__(256)
void gemm_bf16(const u16* __restrict__ A, const u16* __restrict__ Bt,
               const float* __restrict__ bias, void* __restrict__ Cout,
               int N, int K) {
    constexpr int MF = BM / 32;              // m-frags per wave
    __shared__ u16 As[BM * 64];
    __shared__ u16 Bs[128 * 64];
    const int tid = threadIdx.x, w = tid >> 6, l = tid & 63;
    const int g = l >> 4, c = l & 15;
    const int wm = w >> 1, wn = w & 1;
    const int bm = blockIdx.x * BM, bn = blockIdx.y * 128;
    const int sr = l >> 3, sc8 = l & 7;

    const f32x4 zero = {0.f, 0.f, 0.f, 0.f};
    f32x4 acc[MF][4];
    #pragma unroll
    for (int i = 0; i < MF; ++i)
        #pragma unroll
        for (int j = 0; j < 4; ++j) acc[i][j] = zero;

    for (int k0 = 0; k0 < K; k0 += 64) {
        __syncthreads();
        #pragma unroll
        for (int i = 0; i < MF; ++i) {
            const int rb = w * (BM / 4) + i * 8;
            const int r = rb + sr;
            const int ck = (sc8 ^ (r & 7)) * 8;   // source pre-swizzle (involution)
            gl_lds16(A + (size_t)(bm + r) * K + k0 + ck, &As[rb * 64]);
        }
        #pragma unroll
        for (int i = 0; i < 4; ++i) {
            const int rb = w * 32 + i * 8;
            const int r = rb + sr;
            const int ck = (sc8 ^ (r & 7)) * 8;
            gl_lds16(Bt + (size_t)(bn + r) * K + k0 + ck, &Bs[rb * 64]);
        }
        __syncthreads();
        #pragma unroll
        for (int ks = 0; ks < 2; ++ks) {
            bf16x8 af[MF], bfv[4];
            #pragma unroll
            for (int q = 0; q < MF; ++q) {
                const int ra = wm * (BM / 2) + q * 16 + c;
                af[q] = *(const bf16x8*)((const char*)As +
                        ((ra * 128 + ks * 64 + g * 16) ^ ((ra & 7) << 4)));
            }
            #pragma unroll
            for (int q = 0; q < 4; ++q) {
                const int rb2 = wn * 64 + q * 16 + c;
                bfv[q] = *(const bf16x8*)((const char*)Bs +
                        ((rb2 * 128 + ks * 64 + g * 16) ^ ((rb2 & 7) << 4)));
            }
            #pragma unroll
            for (int mf = 0; mf < MF; ++mf)
                #pragma unroll
                for (int nf = 0; nf < 4; ++nf)
                    acc[mf][nf] = __builtin_amdgcn_mfma_f32_16x16x32_bf16(
                        af[mf], bfv[nf], acc[mf][nf], 0, 0, 0);
        }
    }

    #pragma unroll
    for (int mf = 0; mf < MF; ++mf) {
        #pragma unroll
        for (int nf = 0; nf < 4; ++nf) {
            const int n  = bn + wn * 64 + nf * 16 + c;
            const int m0 = bm + wm * (BM / 2) + mf * 16 + g * 4;
            if (EPI == EG_QKV3) {
                u16* o = (u16*)Cout;
                const int seg = n >> 9, nn = n & 511;
                if (seg < 2) {
                    u16* dst = o + (size_t)seg * 4194304;
                    const size_t b0 = (size_t)(nn & 7) * N_TOK * 64 + (nn >> 3);
                    #pragma unroll
                    for (int r = 0; r < 4; ++r)
                        dst[b0 + (size_t)(m0 + r) * 64] = f2b(acc[mf][nf][r]);
                } else {
                    u16* dst = o + (size_t)2 * 4194304;
                    const int h = nn & 7, d = nn >> 3, bb = m0 >> 9, s0 = m0 & 511;
                    u16x4 pk = { f2b(acc[mf][nf][0]), f2b(acc[mf][nf][1]),
                                 f2b(acc[mf][nf][2]), f2b(acc[mf][nf][3]) };
                    *(u16x4*)&dst[((size_t)(h * 16 + bb) * 64 + d) * 512 + s0] = pk;
                }
            } else if (EPI == EG_F32) {
                float* o = (float*)Cout;
                #pragma unroll
                for (int r = 0; r < 4; ++r)
                    o[(size_t)(m0 + r) * N + n] = acc[mf][nf][r];
            } else if (EPI == EG_BIAS_F32) {
                float* o = (float*)Cout;
                const float bv = bias[n];
                #pragma unroll
                for (int r = 0; r < 4; ++r)
                    o[(size_t)(m0 + r) * N + n] = acc[mf][nf][r] + bv;
            } else {  // EG_BRELU_B16
                u16* o = (u16*)Cout;
                const float bv = bias[n];
                #pragma unroll
                for (int r = 0; r < 4; ++r)
                    o[(size_t)(m0 + r) * N + n] = f2b(fmaxf(acc[mf][nf][r] + bv, 0.f));
            }
        }
    }
}

// ---------------- fused bf16-MFMA attention, barrier-free --------------------
// block = 64 q-rows of one (h,b); wave owns 16 rows end-to-end.
// swapped QK (mfma(K,Q)): lane holds one q-row (c) -> stats = 2 shuffles.
// P-buffer is wave-private XOR-swizzled LDS, double-buffered per 128-t chunk.
__global__ __launch_bounds__(256, 2)
void attn_mfma(const u16* __restrict__ Qb, const u16* __restrict__ Kb,
               const u16* __restrict__ Vt, const float* __restrict__ ga,
               const float* __restrict__ ba, u16* __restrict__ A, float scale) {
    __shared__ __align__(16) u16 P[4][2][16][136];   // [wave][dbuf][q-row][t-chunk]
    const int bid = blockIdx.x;
    const int hb = bid & 127, qc = bid >> 7;         // grid 1024: XCD = hb%8
    const int h = hb >> 4, b = hb & 15;
    const int tid = threadIdx.x, w = tid >> 6, l = tid & 63;
    const int g = l >> 4, c = l & 15;
    const float gah = ga[h], bah = ba[h];
    const size_t qkbase = ((size_t)h * N_TOK + (size_t)b * SEQ) * 64;
    const size_t vtbase = ((size_t)(h * 16 + b)) * 64 * 512;
    const int q0 = qc * 64 + w * 16;                 // wave's q rows
    const int swz = (c & 7) << 4;

    // Q B-frags: lane col = c -> q-row q0+c
    const u16* qrow = Qb + qkbase + (size_t)(q0 + c) * 64;
    const bf16x8 qf0 = *(const bf16x8*)(qrow + g * 8);
    const bf16x8 qf1 = *(const bf16x8*)(qrow + 32 + g * 8);

    // ---- QK^T: 32 t-tiles; lane (c,g) gets S[t=tile*16+g*4+r][q-row c] ------
    f32x4 acc[32];
    #pragma unroll
    for (int t = 0; t < 32; ++t) {
        const u16* krow = Kb + qkbase + (size_t)(t * 16 + c) * 64;
        const bf16x8 kf0 = *(const bf16x8*)(krow + g * 8);
        const bf16x8 kf1 = *(const bf16x8*)(krow + 32 + g * 8);
        f32x4 z = {0.f, 0.f, 0.f, 0.f};
        z = __builtin_amdgcn_mfma_f32_16x16x32_bf16(kf0, qf0, z, 0, 0, 0);
        z = __builtin_amdgcn_mfma_f32_16x16x32_bf16(kf1, qf1, z, 0, 0, 0);
        acc[t] = z;
    }

    // ---- row stats for q-row c: per-lane partial + 2 shuffles ---------------
    float sm = 0.f, sq = 0.f;
    #pragma unroll
    for (int t = 0; t < 32; ++t)
        #pragma unroll
        for (int r = 0; r < 4; ++r) {
            const float v = acc[t][r];
            sm += v; sq = fmaf(v, v, sq);
        }
    sm += __shfl_xor(sm, 16); sm += __shfl_xor(sm, 32);
    sq += __shfl_xor(sq, 16); sq += __shfl_xor(sq, 32);

    const float LOG2E = 1.4426950408889634f;
    const float S  = sm * scale;
    const float Qq = sq * scale * scale;
    const float mu = S * (1.f / 512.f);
    const float var = (Qq - 512.f * mu * mu) * (1.f / 511.f);
    const float rg = rsqrtf(var + 1e-8f) * gah;
    const float A2 = scale * rg * LOG2E;
    const float B2 = (bah - mu * rg) * LOG2E;

    // ---- per 128-t chunk: exp -> P_lds (wave-private) -> PV -----------------
    float se = 0.f;
    f32x4 oacc[4];
    #pragma unroll
    for (int dt = 0; dt < 4; ++dt) oacc[dt] = (f32x4){0.f, 0.f, 0.f, 0.f};

    #pragma unroll
    for (int ch = 0; ch < 4; ++ch) {
        char* pbase = (char*)&P[w][ch & 1][0][0];
        #pragma unroll
        for (int tt = 0; tt < 8; ++tt) {
            const int t = ch * 8 + tt;
            float p0 = exp2f(fmaf(acc[t][0], A2, B2));
            float p1 = exp2f(fmaf(acc[t][1], A2, B2));
            float p2 = exp2f(fmaf(acc[t][2], A2, B2));
            float p3 = exp2f(fmaf(acc[t][3], A2, B2));
            se += (p0 + p1) + (p2 + p3);
            u16x4 pk = { f2b(p0), f2b(p1), f2b(p2), f2b(p3) };
            // P[row=c][t_local = tt*16 + g*4 .. +3], XOR-swizzled bytes
            *(u16x4*)(pbase + c * 272 + ((tt * 32 + g * 8) ^ swz)) = pk;
        }
        #pragma unroll
        for (int ks = 0; ks < 4; ++ks) {
            // A-frag: P rows = q-rows; lane row = c, k-slice g
            const bf16x8 pf = *(const bf16x8*)(pbase + c * 272 + ((ks * 64 + g * 16) ^ swz));
            #pragma unroll
            for (int dt = 0; dt < 4; ++dt) {
                const bf16x8 vf = *(const bf16x8*)(Vt + vtbase +
                        (size_t)(dt * 16 + c) * 512 + ch * 128 + ks * 32 + g * 8);
                oacc[dt] = __builtin_amdgcn_mfma_f32_16x16x32_bf16(pf, vf, oacc[dt], 0, 0, 0);
            }
        }
    }

    // ---- softmax denom + output: lane holds q-rows g*4+r, d = dt*16+c -------
    se += __shfl_xor(se, 16); se += __shfl_xor(se, 32);
    const float inv = 1.f / se;          // for q-row c
    float iv[4];
    #pragma unroll
    for (int r = 0; r < 4; ++r) iv[r] = __shfl(inv, g * 4 + r);
    #pragma unroll
    for (int dt = 0; dt < 4; ++dt)
        #pragma unroll
        for (int r = 0; r < 4; ++r)
            A[((size_t)(b * 512 + q0 + g * 4 + r)) * 512 + h * 64 + dt * 16 + c] =
                f2b(oacc[dt][r] * iv[r]);
}

// ---------------- LayerNorm(X + R); optional outputs -------------------------
__global__ __launch_bounds__(256)
void ln_res_kernel(const float* __restrict__ X, const float* __restrict__ R,
                   const float* __restrict__ gp, const float* __restrict__ bp,
                   int lidx, float* __restrict__ Y, u16* __restrict__ Yb,
                   float* __restrict__ Cacc, u16* __restrict__ Cb) {
    const int tid = threadIdx.x, w = tid >> 6, l = tid & 63;
    const size_t row = (size_t)blockIdx.x * 4 + w;
    const float g = gp[lidx], bb = bp[lidx];
    const float* x = X + row * 512;
    const float* r = R + row * 512;
    float v[8];
    const float4 a0 = *(const float4*)&x[l * 8], a1 = *(const float4*)&x[l * 8 + 4];
    const float4 r0 = *(const float4*)&r[l * 8], r1 = *(const float4*)&r[l * 8 + 4];
    v[0] = a0.x + r0.x; v[1] = a0.y + r0.y; v[2] = a0.z + r0.z; v[3] = a0.w + r0.w;
    v[4] = a1.x + r1.x; v[5] = a1.y + r1.y; v[6] = a1.z + r1.z; v[7] = a1.w + r1.w;
    float s = 0.f, sq = 0.f;
    #pragma unroll
    for (int i = 0; i < 8; ++i) { s += v[i]; sq = fmaf(v[i], v[i], sq); }
    #pragma unroll
    for (int o = 1; o < 64; o <<= 1) { s += __shfl_xor(s, o); sq += __shfl_xor(sq, o); }
    const float mu   = s * (1.f / 512.f);
    const float var  = (sq - 512.f * mu * mu) * (1.f / 511.f);
    const float rstd = rsqrtf(var + 1e-8f);
    float y[8];
    #pragma unroll
    for (int i = 0; i < 8; ++i) y[i] = fmaf((v[i] - mu) * rstd, g, bb);
    if (Y) {
        *(float4*)&Y[row * 512 + l * 8]     = *(float4*)&y[0];
        *(float4*)&Y[row * 512 + l * 8 + 4] = *(float4*)&y[4];
    }
    if (Yb) {
        u16x8 yb;
        #pragma unroll
        for (int i = 0; i < 8; ++i) yb[i] = f2b(y[i]);
        *(u16x8*)&Yb[row * 512 + l * 8] = yb;
    }
    if (Cacc) {
        float cv[8];
        float4 c0 = *(float4*)&Cacc[row * 512 + l * 8];
        float4 c1 = *(float4*)&Cacc[row * 512 + l * 8 + 4];
        cv[0] = c0.x + y[0]; cv[1] = c0.y + y[1]; cv[2] = c0.z + y[2]; cv[3] = c0.w + y[3];
        cv[4] = c1.x + y[4]; cv[5] = c1.y + y[5]; cv[6] = c1.z + y[6]; cv[7] = c1.w + y[7];
        *(float4*)&Cacc[row * 512 + l * 8]     = *(float4*)&cv[0];
        *(float4*)&Cacc[row * 512 + l * 8 + 4] = *(float4*)&cv[4];
        u16x8 cb;
        #pragma unroll
        for (int i = 0; i < 8; ++i) cb[i] = f2b(cv[i]);
        *(u16x8*)&Cb[row * 512 + l * 8] = cb;
    }
}

// ---------------- final head: x9 = X8 @ V_e ----------------------------------
__global__ __launch_bounds__(256)
void fin_ve_kernel(const float* __restrict__ X8, const float* __restrict__ Ve,
                   float* __restrict__ x9) {
    const int tid = threadIdx.x, w = tid >> 6, l = tid & 63;
    const size_t row = (size_t)blockIdx.x * 4 + w;
    const float* x = X8 + row * 512;
    float s = 0.f;
    #pragma unroll
    for (int i = 0; i < 8; ++i) s = fmaf(x[l * 8 + i], Ve[l * 8 + i], s);
    #pragma unroll
    for (int o = 1; o < 64; o <<= 1) s += __shfl_xor(s, o);
    if (l == 0) x9[row] = s;
}

// ---------------- z[b,c] = sum_s x9[b,s] * Vd[s,c] ---------------------------
__global__ __launch_bounds__(256)
void fin_vd_kernel(const float* __restrict__ x9, const float* __restrict__ Vd,
                   float* __restrict__ z) {
    __shared__ float red[4][16][65];
    const int tid = threadIdx.x, l = tid & 63, sch = tid >> 6;
    const int c = blockIdx.x * 64 + l;
    float acc[16];
    #pragma unroll
    for (int b = 0; b < 16; ++b) acc[b] = 0.f;
    if (c < NCLS) {
        for (int s = sch * 128; s < sch * 128 + 128; ++s) {
            const float vd = Vd[(size_t)s * NCLS + c];
            #pragma unroll
            for (int b = 0; b < 16; ++b) acc[b] = fmaf(x9[b * 512 + s], vd, acc[b]);
        }
    }
    #pragma unroll
    for (int b = 0; b < 16; ++b) red[sch][b][l] = acc[b];
    __syncthreads();
    if (sch == 0 && c < NCLS) {
        #pragma unroll
        for (int b = 0; b < 16; ++b)
            z[(size_t)b * NCLS + c] = red[0][b][l] + red[1][b][l] + red[2][b][l] + red[3][b][l];
    }
}

// ---------------- final norm (ddof=1 over 10000) + softmax -------------------
__global__ __launch_bounds__(256)
void fin_sm_kernel(const float* __restrict__ z, const float* __restrict__ gp,
                   const float* __restrict__ bp, float* __restrict__ out) {
    __shared__ float zs[NCLS];
    __shared__ float red[4];
    __shared__ float red2[4];
    const int b = blockIdx.x, tid = threadIdx.x, w = tid >> 6, l = tid & 63;
    float s = 0.f, sq = 0.f;
    for (int i = tid; i < NCLS; i += 256) {
        const float v = z[(size_t)b * NCLS + i];
        zs[i] = v; s += v; sq = fmaf(v, v, sq);
    }
    #pragma unroll
    for (int o = 1; o < 64; o <<= 1) { s += __shfl_xor(s, o); sq += __shfl_xor(sq, o); }
    if (l == 0) { red[w] = s; red2[w] = sq; }
    __syncthreads();
    s  = red[0] + red[1] + red[2] + red[3];
    sq = red2[0] + red2[1] + red2[2] + red2[3];
    const float mu   = s / 10000.f;
    const float var  = (sq - 10000.f * mu * mu) / 9999.f;
    const float rstd = rsqrtf(var + 1e-8f);
    const float g = gp[0], be = bp[0];
    __syncthreads();
    float mx = -1e30f;
    for (int i = tid; i < NCLS; i += 256) {
        const float e = fmaf((zs[i] - mu) * rstd, g, be);
        zs[i] = e; mx = fmaxf(mx, e);
    }
    #pragma unroll
    for (int o = 1; o < 64; o <<= 1) mx = fmaxf(mx, __shfl_xor(mx, o));
    if (l == 0) red[w] = mx;
    __syncthreads();
    mx = fmaxf(fmaxf(red[0], red[1]), fmaxf(red[2], red[3]));
    float es = 0.f;
    for (int i = tid; i < NCLS; i += 256) {
        const float p = expf(zs[i] - mx);
        zs[i] = p; es += p;
    }
    #pragma unroll
    for (int o = 1; o < 64; o <<= 1) es += __shfl_xor(es, o);
    if (l == 0) red2[w] = es;
    __syncthreads();
    es = red2[0] + red2[1] + red2[2] + red2[3];
    const float inv = 1.f / es;
    for (int i = tid; i < NCLS; i += 256) out[(size_t)b * NCLS + i] = zs[i] * inv;
}

// =============================================================================
extern "C" void kernel_launch(void* const* d_in, const int* in_sizes, int n_in,
                              void* d_out, int out_size, void* d_ws, size_t ws_size,
                              hipStream_t stream) {
    (void)in_sizes; (void)n_in; (void)out_size; (void)ws_size;
    const int*   xi  = (const int*)d_in[0];
    const float* emb = (const float*)d_in[1];
    const float* WQ  = (const float*)d_in[2];
    const float* WK  = (const float*)d_in[3];
    const float* WV  = (const float*)d_in[4];
    const float* WO  = (const float*)d_in[5];
    const float* W1  = (const float*)d_in[6];
    const float* b1  = (const float*)d_in[7];
    const float* W2  = (const float*)d_in[8];
    const float* b2  = (const float*)d_in[9];
    const float* ga  = (const float*)d_in[10];
    const float* ba  = (const float*)d_in[11];
    const float* g1  = (const float*)d_in[12];
    const float* be1 = (const float*)d_in[13];
    const float* g2  = (const float*)d_in[14];
    const float* be2 = (const float*)d_in[15];
    const float* Ve  = (const float*)d_in[16];
    const float* Vd  = (const float*)d_in[17];
    const float* gf  = (const float*)d_in[18];
    const float* bf  = (const float*)d_in[19];
    float* out = (float*)d_out;

    // ---------------- workspace layout ----------------
    float* ws  = (float*)d_ws;
    float* pos = ws;                        // 262144 f
    float* C   = pos + 262144;              // 4M f
    float* X2  = C   + 4194304;
    float* OUT = X2  + 4194304;
    float* PF  = OUT + 4194304;
    u16* ub = (u16*)(PF + 4194304);
    u16* Cb  = ub;  ub += 4194304;          // bf16 carry [8192][512]
    u16* X2b = ub;  ub += 4194304;          // bf16 x2    [8192][512]
    u16* Qbf = ub;  ub += 4194304;          // [H][8192][64]; K at +4M, Vt at +8M
    u16* Kbf = ub;  ub += 4194304;
    u16* Vtb = ub;  ub += 4194304;          // [H*16][64][512]
    u16* Abf = ub;  ub += 4194304;          // attn out bf16 [8192][512]
    u16* Hb  = Qbf;                         // FF hidden [8192][2048] aliases Q|K|Vt|A
    u16* WQKVb = ub; ub += 4718592;         // 6 x [1536][512]
    u16* WOt = ub; ub += 1572864;           // 6 x [512][512] (transposed)
    u16* W1t = ub; ub += 6291456;           // 6 x [2048][512] (transposed)
    u16* W2t = ub; ub += 6291456;           // 6 x [512][2048] (transposed)
    float* x9 = (float*)ub;                 // 8192 f
    float* zb = x9 + 8192;                  // 160000 f

    pos_kernel<<<16, 512, 0, stream>>>(pos);
    embed_kernel<<<4096, 256, 0, stream>>>(xi, emb, pos, C, Cb);

    cvt3_kernel<<<4608, 256, 0, stream>>>(WQ, WK, WV, WQKVb);
    tcvt_b16_kernel<<<dim3(8,  8, 6), 256, 0, stream>>>(WO, WOt, 512, 512);
    tcvt_b16_kernel<<<dim3(8, 32, 6), 256, 0, stream>>>(W1, W1t, 512, 2048);
    tcvt_b16_kernel<<<dim3(32, 8, 6), 256, 0, stream>>>(W2, W2t, 2048, 512);

    const float scale = 1.0f / sqrtf(512.0f);

    for (int l = 0; l < NLAYER; ++l) {
        const u16* wqkv = WQKVb + (size_t)l * 786432;
        const u16* wo = WOt + (size_t)l * 262144;
        const u16* w1 = W1t + (size_t)l * 1048576;
        const u16* w2 = W2t + (size_t)l * 1048576;

        gemm_bf16<128, EG_QKV3>     <<<dim3(64, 12), 256, 0, stream>>>(Cb, wqkv, nullptr, Qbf, 1536, 512);
        attn_mfma                   <<<1024, 256, 0, stream>>>(Qbf, Kbf, Vtb, ga + l*8, ba + l*8, Abf, scale);
        gemm_bf16<64, EG_F32>       <<<dim3(128, 4), 256, 0, stream>>>(Abf, wo, nullptr, PF, 512, 512);
        ln_res_kernel               <<<2048, 256, 0, stream>>>(PF, C, g1, be1, l, X2, X2b, nullptr, nullptr);
        gemm_bf16<128, EG_BRELU_B16><<<dim3(64, 16), 256, 0, stream>>>(X2b, w1, b1 + l*2048, Hb, 2048, 512);
        gemm_bf16<64, EG_BIAS_F32>  <<<dim3(128, 4), 256, 0, stream>>>(Hb, w2, b2 + l*512, PF, 512, 2048);
        ln_res_kernel               <<<2048, 256, 0, stream>>>(PF, X2, g2, be2, l,
                                                               (l == NLAYER - 1) ? OUT : nullptr,
                                                               nullptr, C, Cb);
    }

    fin_ve_kernel<<<2048, 256, 0, stream>>>(OUT, Ve, x9);
    fin_vd_kernel<<<157,  256, 0, stream>>>(x9, Vd, zb);
    fin_sm_kernel<<<16,   256, 0, stream>>>(zb, gf, bf, out);
}